// Round 15
// baseline (669.762 us; speedup 1.0000x reference)
//
#include <hip/hip_runtime.h>
#include <math.h>

#define N_NODES 50000
#define N_EDGES 400000
#define C 32
#define NB 8
#define HID 64
#define NL 2
#define NG 64
#define RMAXF 5.0f
#define EPSF 1e-5f
#define TBL 4096
#define BN_BLOCKS 512
#define NBLK_N ((N_NODES + 255) / 256)   // 196

__device__ __forceinline__ float silu_f(float x) { return x / (1.0f + __expf(-x)); }
__device__ __forceinline__ float sigmoid_f(float x) { return 1.0f / (1.0f + __expf(-x)); }
__device__ __forceinline__ void atomAddF(float* p, float val) {
  __hip_atomic_fetch_add(p, val, __ATOMIC_RELAXED, __HIP_MEMORY_SCOPE_AGENT);
}
__device__ __forceinline__ void atomAddD(double* p, double val) {
  __hip_atomic_fetch_add(p, val, __ATOMIC_RELAXED, __HIP_MEMORY_SCOPE_AGENT);
}
__device__ __forceinline__ unsigned short bf16_rne(float f) {
  unsigned u = __float_as_uint(f);
  return (unsigned short)((u + 0x7FFFu + ((u >> 16) & 1u)) >> 16);
}
__device__ __forceinline__ float bfu(unsigned short u) {
  return __uint_as_float(((unsigned)u) << 16);
}

// ---------------- fb-only edge geometry (with basis) ----------------
__global__ __launch_bounds__(256) void k_edge_geom(
    const float* __restrict__ pos, const int* __restrict__ ei,
    const float* __restrict__ freqs,
    float* __restrict__ basis, float* __restrict__ Y1)
{
  int e = blockIdx.x * 256 + threadIdx.x;
  if (e >= N_EDGES) return;
  int s = ei[e], d = ei[N_EDGES + e];
  float vx = pos[d*3+0] - pos[s*3+0];
  float vy = pos[d*3+1] - pos[s*3+1];
  float vz = pos[d*3+2] - pos[s*3+2];
  float dist = sqrtf(vx*vx + vy*vy + vz*vz);
  float invd = 1.0f / fmaxf(dist, 1e-9f);
  Y1[e*3+0] = vx*invd; Y1[e*3+1] = vy*invd; Y1[e*3+2] = vz*invd;
  float x = fminf(fmaxf(dist * (1.0f/RMAXF), 0.0f), 1.0f);
  float x2 = x*x, x3 = x2*x;
  float cut = 1.0f - x3 * (10.0f - 15.0f*x + 6.0f*x2);
  if (dist > RMAXF) cut = 0.0f;
  float rinv = cut / fmaxf(dist, 1e-6f);
  #pragma unroll
  for (int k = 0; k < NB; k++)
    basis[e*NB + k] = sinf(freqs[k] * dist) * rinv;
}

// ---------------- node init: s fp32 + s_bf bf16 ----------------
__global__ __launch_bounds__(256) void k_node_init(
    const int* __restrict__ species, const float* __restrict__ emb,
    float* __restrict__ s, unsigned short* __restrict__ s_bf)
{
  int i = blockIdx.x * 256 + threadIdx.x;
  if (i >= N_NODES * C) return;
  int n = i >> 5, c = i & 31;
  float x = emb[species[n]*C + c];
  s[i] = x;
  s_bf[i] = bf16_rne(x);
}

// ---------------- CSR build ----------------
__global__ __launch_bounds__(256) void k_hist(const int* __restrict__ ei, int* __restrict__ counts)
{
  int e = blockIdx.x * 256 + threadIdx.x;
  if (e >= N_EDGES) return;
  atomicAdd(&counts[ei[N_EDGES + e]], 1);
}

__global__ __launch_bounds__(256) void k_scanA(const int* __restrict__ counts, int* __restrict__ bsum)
{
  __shared__ int sh[256];
  int i = blockIdx.x * 256 + threadIdx.x;
  int x = (i < N_NODES) ? counts[i] : 0;
  sh[threadIdx.x] = x;
  __syncthreads();
  for (int off = 128; off > 0; off >>= 1) {
    if (threadIdx.x < off) sh[threadIdx.x] += sh[threadIdx.x + off];
    __syncthreads();
  }
  if (threadIdx.x == 0) bsum[blockIdx.x] = sh[0];
}

__global__ __launch_bounds__(256) void k_scanB(int* __restrict__ bsum)
{
  __shared__ int sh[256];
  int tid = threadIdx.x;
  int x = (tid < NBLK_N) ? bsum[tid] : 0;
  sh[tid] = x;
  __syncthreads();
  for (int off = 1; off < 256; off <<= 1) {
    int y = (tid >= off) ? sh[tid - off] : 0;
    __syncthreads();
    sh[tid] += y;
    __syncthreads();
  }
  if (tid < NBLK_N) bsum[tid] = sh[tid] - x;   // exclusive
}

__global__ __launch_bounds__(256) void k_scanC(const int* __restrict__ counts,
                                               const int* __restrict__ bsum,
                                               int* __restrict__ row_start)
{
  __shared__ int sh[256];
  int i = blockIdx.x * 256 + threadIdx.x;
  int x = (i < N_NODES) ? counts[i] : 0;
  sh[threadIdx.x] = x;
  __syncthreads();
  for (int off = 1; off < 256; off <<= 1) {
    int y = (threadIdx.x >= off) ? sh[threadIdx.x - off] : 0;
    __syncthreads();
    sh[threadIdx.x] += y;
    __syncthreads();
  }
  if (i < N_NODES) row_start[i] = bsum[blockIdx.x] + sh[threadIdx.x] - x; // exclusive
}

// ---------------- fused geometry + scatter into packed 32B records ----------------
__global__ __launch_bounds__(256) void k_geom_scatter(
    const float* __restrict__ pos, const int* __restrict__ ei,
    const int* __restrict__ row_start, int* __restrict__ cursor,
    float* __restrict__ rec)
{
  int e = blockIdx.x * 256 + threadIdx.x;
  if (e >= N_EDGES) return;
  int s = ei[e], d = ei[N_EDGES + e];
  float vx = pos[d*3+0] - pos[s*3+0];
  float vy = pos[d*3+1] - pos[s*3+1];
  float vz = pos[d*3+2] - pos[s*3+2];
  float dist = sqrtf(vx*vx + vy*vy + vz*vz);
  float invd = 1.0f / fmaxf(dist, 1e-9f);
  int p = row_start[d] + atomicAdd(&cursor[d], 1);
  float* rp = rec + (size_t)p * 8;
  float4 r0; r0.x = dist; r0.y = __int_as_float(s); r0.z = vx*invd; r0.w = vy*invd;
  *(float4*)rp = r0;
  rp[4] = vz*invd;
}

// ---------------- radial-MLP tabulation ----------------
__global__ __launch_bounds__(256) void k_table_h(
    const float* __restrict__ freqs,
    const float* __restrict__ rW1, const float* __restrict__ rb1,
    const float* __restrict__ rW2, const float* __restrict__ rb2,
    float* __restrict__ h2tab)                 // [NL*TBL*HID]
{
  int idx = blockIdx.x * 256 + threadIdx.x;    // [NL*TBL]
  if (idx >= NL * TBL) return;
  int l = idx / TBL, i = idx - l * TBL;
  float d = (float)i * (RMAXF / (float)(TBL - 1));
  float x = fminf(fmaxf(d * (1.0f/RMAXF), 0.0f), 1.0f);
  float x2 = x*x, x3 = x2*x;
  float cut = 1.0f - x3 * (10.0f - 15.0f*x + 6.0f*x2);
  float rinv = cut / fmaxf(d, 1e-6f);
  float bas[NB];
  #pragma unroll
  for (int k = 0; k < NB; k++) bas[k] = sinf(freqs[k] * d) * rinv;

  const float* W1 = rW1 + l*NB*HID;
  const float* B1 = rb1 + l*HID;
  const float* W2 = rW2 + l*HID*HID;
  const float* B2 = rb2 + l*HID;

  float h2[HID];
  #pragma unroll
  for (int j = 0; j < HID; j++) h2[j] = B2[j];
  #pragma unroll 2
  for (int k = 0; k < HID; k++) {
    float t = B1[k];
    #pragma unroll
    for (int b = 0; b < NB; b++) t = fmaf(bas[b], W1[b*HID + k], t);
    float h1k = silu_f(t);
    const float* r = W2 + k*HID;
    #pragma unroll
    for (int j = 0; j < HID; j++) h2[j] = fmaf(h1k, r[j], h2[j]);
  }
  float* out = h2tab + (size_t)idx * HID;
  #pragma unroll
  for (int j = 0; j < HID; j++) out[j] = silu_f(h2[j]);
}

__global__ __launch_bounds__(256) void k_table_w(
    const float* __restrict__ h2tab,
    const float* __restrict__ rW3, const float* __restrict__ rb3,
    float* __restrict__ wtab)                  // [NL*TBL*128]
{
  int idx = blockIdx.x * 256 + threadIdx.x;    // [NL*TBL*16]
  if (idx >= NL * TBL * 16) return;
  int chunk = idx & 15;
  int row   = idx >> 4;                        // l*TBL + i
  int l     = row / TBL;
  const float* h2 = h2tab + (size_t)row * HID;
  const float* W3 = rW3 + l*HID*4*C + chunk*8;
  const float* B3 = rb3 + l*4*C + chunk*8;
  float a[8];
  #pragma unroll
  for (int ci = 0; ci < 8; ci++) a[ci] = B3[ci];
  #pragma unroll 4
  for (int k = 0; k < HID; k++) {
    float h = h2[k];
    #pragma unroll
    for (int ci = 0; ci < 8; ci++) a[ci] = fmaf(h, W3[k*4*C + ci], a[ci]);
  }
  float* out = wtab + (size_t)row * 128 + chunk*8;
  #pragma unroll
  for (int ci = 0; ci < 8; ci++) out[ci] = a[ci];
}

// ---------------- aggregate: packed records, pipelined, layer-specialized ---------
// HAS_V=false (layer 0): v==0 exactly -> no v gather (saves 192B/edge, the dominant
// traffic), asg=0 (gate=sigmoid(0)), m_v = w3*xs*Y1.
// HAS_V=true: v_bf4 padded ushort4 -> one aligned 8B load (was 3 sub-dword loads).
template<bool HAS_V>
__global__ __launch_bounds__(256) void k_agg_update(
    const float* __restrict__ tb,              // this layer's wtab [TBL][128]
    const float* __restrict__ rec,
    const int* __restrict__ row_start, const int* __restrict__ counts,
    const unsigned short* __restrict__ s_bf, const unsigned short* __restrict__ v_bf4,
    const float* __restrict__ Wss, const float* __restrict__ bss,
    const float* __restrict__ Wvv,
    float* __restrict__ s_new, float* __restrict__ v_new)
{
  int t = blockIdx.x * 256 + threadIdx.x;
  int n = t >> 5;
  int c = t & 31;

  const float SCALE = (float)(TBL - 1) / RMAXF;
  float asf = 0.0f, asg = 0.0f, av0 = 0.0f, av1 = 0.0f, av2 = 0.0f;
  int beg = row_start[n], cnt = counts[n];

  if (cnt > 0) {
    int last = beg + cnt - 1;
    int pA = beg, pB = (beg + 1 < last) ? beg + 1 : last;
    float4 rA = *(const float4*)(rec + (size_t)pA * 8);
    float  zA = rec[(size_t)pA * 8 + 4];
    float4 rB = *(const float4*)(rec + (size_t)pB * 8);
    float  zB = rec[(size_t)pB * 8 + 4];

    for (int i = 0; i < cnt; i += 2) {
      int pA2 = beg + i + 2; pA2 = pA2 < last ? pA2 : last;
      int pB2 = beg + i + 3; pB2 = pB2 < last ? pB2 : last;
      float4 rA_n = *(const float4*)(rec + (size_t)pA2 * 8);
      float  zA_n = rec[(size_t)pA2 * 8 + 4];
      float4 rB_n = *(const float4*)(rec + (size_t)pB2 * 8);
      float  zB_n = rec[(size_t)pB2 * 8 + 4];

      float validB = (i + 1 < cnt) ? 1.0f : 0.0f;
      float dA = rA.x;  int srcA = __float_as_int(rA.y);
      float yA0 = rA.z, yA1 = rA.w, yA2 = zA;
      float dB = rB.x;  int srcB = __float_as_int(rB.y);
      float yB0 = rB.z, yB1 = rB.w, yB2 = zB;

      // feature gathers (independent A/B chains)
      float xsA = bfu(s_bf[srcA*C + c]);
      float xsB = bfu(s_bf[srcB*C + c]);
      float xvA0 = 0.0f, xvA1 = 0.0f, xvA2 = 0.0f;
      float xvB0 = 0.0f, xvB1 = 0.0f, xvB2 = 0.0f;
      if (HAS_V) {
        ushort4 a4 = *(const ushort4*)(v_bf4 + (size_t)(srcA*C + c)*4);
        ushort4 b4 = *(const ushort4*)(v_bf4 + (size_t)(srcB*C + c)*4);
        xvA0 = bfu(a4.x); xvA1 = bfu(a4.y); xvA2 = bfu(a4.z);
        xvB0 = bfu(b4.x); xvB1 = bfu(b4.y); xvB2 = bfu(b4.z);
      }

      // table lerp
      float tsA = fminf(dA, RMAXF) * SCALE;
      int t0A = (int)tsA; t0A = t0A > TBL-2 ? TBL-2 : t0A;
      float frA = tsA - (float)t0A;
      float tsB = fminf(dB, RMAXF) * SCALE;
      int t0B = (int)tsB; t0B = t0B > TBL-2 ? TBL-2 : t0B;
      float frB = tsB - (float)t0B;

      const float* rtA0 = tb + (size_t)t0A * 128 + c;
      const float* rtA1 = rtA0 + 128;
      const float* rtB0 = tb + (size_t)t0B * 128 + c;
      const float* rtB1 = rtB0 + 128;

      float w1A = fmaf(frA, rtA1[0]  - rtA0[0],  rtA0[0]);
      float w3A = fmaf(frA, rtA1[64] - rtA0[64], rtA0[64]);
      float w1B = validB * fmaf(frB, rtB1[0]  - rtB0[0],  rtB0[0]);
      float w3B = validB * fmaf(frB, rtB1[64] - rtB0[64], rtB0[64]);

      asf = fmaf(w1A, xsA, asf);
      float w3xsA = w3A * xsA;
      asf = fmaf(w1B, xsB, asf);
      float w3xsB = w3B * xsB;

      if (HAS_V) {
        float w2A = fmaf(frA, rtA1[32] - rtA0[32], rtA0[32]);
        float w4A = fmaf(frA, rtA1[96] - rtA0[96], rtA0[96]);
        float w2B = validB * fmaf(frB, rtB1[32] - rtB0[32], rtB0[32]);
        float w4B = validB * fmaf(frB, rtB1[96] - rtB0[96], rtB0[96]);
        asg = fmaf(w2A, xvA0*yA0 + xvA1*yA1 + xvA2*yA2, asg);
        asg = fmaf(w2B, xvB0*yB0 + xvB1*yB1 + xvB2*yB2, asg);
        av0 += fmaf(w3xsA, yA0, w4A*xvA0) + fmaf(w3xsB, yB0, w4B*xvB0);
        av1 += fmaf(w3xsA, yA1, w4A*xvA1) + fmaf(w3xsB, yB1, w4B*xvB1);
        av2 += fmaf(w3xsA, yA2, w4A*xvA2) + fmaf(w3xsB, yB2, w4B*xvB2);
      } else {
        av0 += fmaf(w3xsA, yA0, w3xsB * yB0);
        av1 += fmaf(w3xsA, yA1, w3xsB * yB1);
        av2 += fmaf(w3xsA, yA2, w3xsB * yB2);
      }

      rA = rA_n; zA = zA_n; rB = rB_n; zB = zB_n;
    }
  }

  float sgv  = silu_f(asf);
  float gate = sigmoid_f(asg);               // asg==0 for layer 0 -> 0.5, matches ref
  float vg0 = gate*av0, vg1 = gate*av1, vg2 = gate*av2;

  // self-interaction: 32x32 mix via lane broadcast
  float sn = bss[c];
  float vm0 = 0.0f, vm1 = 0.0f, vm2 = 0.0f;
  #pragma unroll
  for (int k = 0; k < C; k++) {
    float a  = __shfl(sgv, k, 32);
    sn = fmaf(a, Wss[k*C + c], sn);
    float wv = Wvv[k*C + c];
    vm0 = fmaf(__shfl(vg0, k, 32), wv, vm0);
    vm1 = fmaf(__shfl(vg1, k, 32), wv, vm1);
    vm2 = fmaf(__shfl(vg2, k, 32), wv, vm2);
  }

  s_new[n*C + c] = sn;
  float* vo = v_new + (size_t)(n*C + c)*3;
  vo[0] = vm0; vo[1] = vm1; vo[2] = vm2;
}

// ---------------- BN stats (grid-stride, register accumulation) ----------------
__global__ __launch_bounds__(256) void k_bn_stats(
    const float* __restrict__ s_new, const float* __restrict__ v_new,
    double* __restrict__ bn_sums)
{
  __shared__ float lacc[3*C];
  if (threadIdx.x < 3*C) lacc[threadIdx.x] = 0.0f;
  __syncthreads();
  int c = threadIdx.x & 31;
  float r1 = 0.0f, r2 = 0.0f, r3 = 0.0f;
  const int NC = N_NODES * C;
  for (int i = blockIdx.x * 256 + threadIdx.x; i < NC; i += BN_BLOCKS * 256) {
    float sn = s_new[i];
    const float* vp = v_new + (size_t)i * 3;
    r1 += sn;
    r2 += sn * sn;
    r3 += vp[0]*vp[0] + vp[1]*vp[1] + vp[2]*vp[2];
  }
  atomicAdd(&lacc[c],       r1);
  atomicAdd(&lacc[C + c],   r2);
  atomicAdd(&lacc[2*C + c], r3);
  __syncthreads();
  if (threadIdx.x < 3*C) atomAddD(&bn_sums[threadIdx.x], (double)lacc[threadIdx.x]);
}

// ---------------- apply BN + residual + bf16 mirror; FIRST: v write-direct;
//                  LAST: fused readout (shfl-reduce + 1 atomic per node) ----------
template<bool FIRST, bool LAST>
__global__ __launch_bounds__(256) void k_apply(
    const float* __restrict__ s_new, const float* __restrict__ v_new,
    const double* __restrict__ bn_sums,
    const float* __restrict__ gs, const float* __restrict__ gv,
    const float* __restrict__ bn_bs,
    float* __restrict__ s, float* __restrict__ v,
    unsigned short* __restrict__ s_bf, unsigned short* __restrict__ v_bf4,
    const int* __restrict__ species, const int* __restrict__ batch,
    const float* __restrict__ W_out, const float* __restrict__ b_out,
    const float* __restrict__ atom_ref, float* __restrict__ out)
{
  int i = blockIdx.x * 256 + threadIdx.x;
  if (i >= N_NODES * C) return;
  int c = i & 31;
  int n = i >> 5;
  double S1 = bn_sums[c], S2 = bn_sums[C + c], VN = bn_sums[2*C + c];
  float mu  = (float)(S1 / (double)N_NODES);
  float var = (float)(S2 / (double)N_NODES) - mu*mu;
  float vn2 = (float)(VN / (3.0 * (double)N_NODES));
  float ssc = gs[c] / sqrtf(var + EPSF);
  float vsc = gv[c] / sqrtf(vn2 + EPSF);

  float sv = s[i] + (s_new[i] - mu) * ssc + bn_bs[c];
  s[i] = sv;
  s_bf[i] = bf16_rne(sv);
  float* vp = v + (size_t)i*3;
  const float* vn = v_new + (size_t)i*3;
  ushort4 vb;
  float vv0 = (FIRST ? 0.0f : vp[0]) + vn[0] * vsc;
  float vv1 = (FIRST ? 0.0f : vp[1]) + vn[1] * vsc;
  float vv2 = (FIRST ? 0.0f : vp[2]) + vn[2] * vsc;
  vp[0] = vv0; vp[1] = vv1; vp[2] = vv2;
  vb.x = bf16_rne(vv0); vb.y = bf16_rne(vv1); vb.z = bf16_rne(vv2); vb.w = 0;
  *(ushort4*)(v_bf4 + (size_t)i*4) = vb;

  if (LAST) {
    float e = sv * W_out[c];
    #pragma unroll
    for (int off = 16; off > 0; off >>= 1) e += __shfl_down(e, off, 32);
    if (c == 0) {
      e += b_out[0] + atom_ref[species[n]];
      atomAddF(&out[batch[n]], e);
    }
  }
}

// ================= FALLBACK (atomic path, used only if ws too small) ==========
__global__ __launch_bounds__(256) void k_edge_msg_fb(
    const float* __restrict__ basis, const float* __restrict__ Y1,
    const int* __restrict__ ei,
    const float* __restrict__ s, const float* __restrict__ v,
    const float* __restrict__ rW1, const float* __restrict__ rb1,
    const float* __restrict__ rW2, const float* __restrict__ rb2,
    const float* __restrict__ rW3, const float* __restrict__ rb3,
    float* __restrict__ agg_sf, float* __restrict__ agg_sg, float* __restrict__ agg_v)
{
  int e = blockIdx.x * 256 + threadIdx.x;
  if (e >= N_EDGES) return;
  int src = ei[e], dst = ei[N_EDGES + e];
  const float4 b0 = *(const float4*)(basis + (size_t)e*NB);
  const float4 b1 = *(const float4*)(basis + (size_t)e*NB + 4);
  float bas[NB] = {b0.x, b0.y, b0.z, b0.w, b1.x, b1.y, b1.z, b1.w};
  float h2[HID];
  #pragma unroll
  for (int j = 0; j < HID; j++) h2[j] = rb2[j];
  #pragma unroll 2
  for (int k = 0; k < HID; k++) {
    float t = rb1[k];
    #pragma unroll
    for (int b = 0; b < NB; b++) t = fmaf(bas[b], rW1[b*HID + k], t);
    float h1k = silu_f(t);
    const float* r = rW2 + k*HID;
    #pragma unroll
    for (int j = 0; j < HID; j++) h2[j] = fmaf(h1k, r[j], h2[j]);
  }
  #pragma unroll
  for (int j = 0; j < HID; j++) h2[j] = silu_f(h2[j]);
  float y0 = Y1[e*3+0], y1 = Y1[e*3+1], y2 = Y1[e*3+2];
  #pragma unroll 1
  for (int cb = 0; cb < 16; cb++) {
    float a[8];
    #pragma unroll
    for (int ci = 0; ci < 8; ci++) a[ci] = rb3[cb*8 + ci];
    #pragma unroll
    for (int k = 0; k < HID; k++) {
      float h = h2[k];
      #pragma unroll
      for (int ci = 0; ci < 8; ci++) a[ci] = fmaf(h, rW3[k*4*C + cb*8 + ci], a[ci]);
    }
    #pragma unroll
    for (int ci = 0; ci < 8; ci++) {
      int o = cb*8 + ci;
      int path = o >> 5;
      int c = o & 31;
      float xs = s[src*C + c];
      const float* vp = v + (size_t)(src*C + c)*3;
      float xv0 = vp[0], xv1 = vp[1], xv2 = vp[2];
      if (path == 0) {
        atomAddF(&agg_sf[dst*C + c], a[ci] * xs);
      } else if (path == 1) {
        atomAddF(&agg_sg[dst*C + c], a[ci] * (xv0*y0 + xv1*y1 + xv2*y2));
      } else if (path == 2) {
        float w3xs = a[ci] * xs;
        float* ap = agg_v + (size_t)(dst*C + c)*3;
        atomAddF(ap+0, w3xs*y0); atomAddF(ap+1, w3xs*y1); atomAddF(ap+2, w3xs*y2);
      } else {
        float* ap = agg_v + (size_t)(dst*C + c)*3;
        atomAddF(ap+0, a[ci]*xv0); atomAddF(ap+1, a[ci]*xv1); atomAddF(ap+2, a[ci]*xv2);
      }
    }
  }
}

__global__ __launch_bounds__(256) void k_node_update_fb(
    const float* __restrict__ agg_sf, const float* __restrict__ agg_sg,
    const float* __restrict__ agg_v,
    const float* __restrict__ Wss, const float* __restrict__ bss,
    const float* __restrict__ Wvv,
    float* __restrict__ s_new, float* __restrict__ v_new,
    double* __restrict__ bn_sums)
{
  __shared__ float lacc[3*C];
  int t = blockIdx.x * 256 + threadIdx.x;
  int n = t >> 5;
  int c = t & 31;
  if (threadIdx.x < 3*C) lacc[threadIdx.x] = 0.0f;
  __syncthreads();
  float asf = agg_sf[n*C + c];
  float asg = agg_sg[n*C + c];
  const float* ap = agg_v + (size_t)(n*C + c)*3;
  float av0 = ap[0], av1 = ap[1], av2 = ap[2];
  float sgv = silu_f(asf);
  float gate = sigmoid_f(asg);
  float vg0 = gate*av0, vg1 = gate*av1, vg2 = gate*av2;
  float sn = bss[c];
  float vm0 = 0.0f, vm1 = 0.0f, vm2 = 0.0f;
  #pragma unroll
  for (int k = 0; k < C; k++) {
    float a  = __shfl(sgv, k, 32);
    sn = fmaf(a, Wss[k*C + c], sn);
    float wv = Wvv[k*C + c];
    vm0 = fmaf(__shfl(vg0, k, 32), wv, vm0);
    vm1 = fmaf(__shfl(vg1, k, 32), wv, vm1);
    vm2 = fmaf(__shfl(vg2, k, 32), wv, vm2);
  }
  s_new[n*C + c] = sn;
  float* vo = v_new + (size_t)(n*C + c)*3;
  vo[0] = vm0; vo[1] = vm1; vo[2] = vm2;
  float vn2 = vm0*vm0 + vm1*vm1 + vm2*vm2;
  atomicAdd(&lacc[c], sn);
  atomicAdd(&lacc[C + c], sn*sn);
  atomicAdd(&lacc[2*C + c], vn2);
  __syncthreads();
  if (threadIdx.x < 3*C) atomAddD(&bn_sums[threadIdx.x], (double)lacc[threadIdx.x]);
}

__global__ void k_bn_scales_fb(const double* __restrict__ bn_sums,
                               const float* __restrict__ gs, const float* __restrict__ gv,
                               float* __restrict__ scales)
{
  int m = threadIdx.x;
  if (m >= C) return;
  double S1 = bn_sums[m], S2 = bn_sums[C + m], VN = bn_sums[2*C + m];
  double mu  = S1 / (double)N_NODES;
  double var = S2 / (double)N_NODES - mu*mu;
  double vn2 = VN / (3.0 * (double)N_NODES);
  scales[m]       = (float)mu;
  scales[C + m]   = gs[m] / sqrtf((float)var + EPSF);
  scales[2*C + m] = gv[m] / sqrtf((float)vn2 + EPSF);
}

__global__ __launch_bounds__(256) void k_apply_fb(
    const float* __restrict__ s_new, const float* __restrict__ v_new,
    const float* __restrict__ scales, const float* __restrict__ bn_bs,
    float* __restrict__ s, float* __restrict__ v)
{
  int i = blockIdx.x * 256 + threadIdx.x;
  if (i >= N_NODES * C) return;
  int c = i & 31;
  s[i] += (s_new[i] - scales[c]) * scales[C + c] + bn_bs[c];
  float vs = scales[2*C + c];
  v[(size_t)i*3+0] += v_new[(size_t)i*3+0] * vs;
  v[(size_t)i*3+1] += v_new[(size_t)i*3+1] * vs;
  v[(size_t)i*3+2] += v_new[(size_t)i*3+2] * vs;
}

__global__ __launch_bounds__(256) void k_readout_fb(
    const float* __restrict__ s, const int* __restrict__ species,
    const int* __restrict__ batch,
    const float* __restrict__ W_out, const float* __restrict__ b_out,
    const float* __restrict__ atom_ref, float* __restrict__ out)
{
  __shared__ float acc[NG];
  if (threadIdx.x < NG) acc[threadIdx.x] = 0.0f;
  __syncthreads();
  int n = blockIdx.x * 256 + threadIdx.x;
  if (n < N_NODES) {
    float e = b_out[0] + atom_ref[species[n]];
    #pragma unroll
    for (int c = 0; c < C; c++) e = fmaf(s[n*C + c], W_out[c], e);
    atomicAdd(&acc[batch[n]], e);
  }
  __syncthreads();
  if (threadIdx.x < NG) {
    float a = acc[threadIdx.x];
    if (a != 0.0f) atomAddF(&out[threadIdx.x], a);
  }
}

extern "C" void kernel_launch(void* const* d_in, const int* in_sizes, int n_in,
                              void* d_out, int out_size, void* d_ws, size_t ws_size,
                              hipStream_t stream)
{
  const int*   species  = (const int*)  d_in[0];
  const float* pos      = (const float*)d_in[1];
  const int*   ei       = (const int*)  d_in[2];
  const int*   batch    = (const int*)  d_in[3];
  const float* emb      = (const float*)d_in[4];
  const float* freqs    = (const float*)d_in[5];
  const float* rW1      = (const float*)d_in[6];
  const float* rb1      = (const float*)d_in[7];
  const float* rW2      = (const float*)d_in[8];
  const float* rb2      = (const float*)d_in[9];
  const float* rW3      = (const float*)d_in[10];
  const float* rb3      = (const float*)d_in[11];
  const float* Wss      = (const float*)d_in[12];
  const float* bss      = (const float*)d_in[13];
  const float* Wvv      = (const float*)d_in[14];
  const float* bn_gs    = (const float*)d_in[15];
  const float* bn_bs    = (const float*)d_in[16];
  const float* bn_gv    = (const float*)d_in[17];
  const float* W_out    = (const float*)d_in[18];
  const float* b_out    = (const float*)d_in[19];
  const float* atom_ref = (const float*)d_in[20];

  float* ws = (float*)d_ws;
  size_t off = 0;
  float* basis  = ws + off; off += (size_t)N_EDGES * NB;     // fb path only
  float* Y1     = ws + off; off += (size_t)N_EDGES * 3;      // fb path only
  float* s      = ws + off; off += (size_t)N_NODES * C;
  float* v      = ws + off; off += (size_t)N_NODES * C * 3;
  float* s_new  = ws + off; off += (size_t)N_NODES * C;
  float* v_new  = ws + off; off += (size_t)N_NODES * C * 3;
  double* bn_sums = (double*)(ws + off); off += 192;
  float* scales = ws + off; off += 96;

  // --- region A (sorted + table path) ---
  size_t ra = off;
  float* rec      = ws + ra;            ra += (size_t)N_EDGES * 8;
  int*   counts   = (int*)(ws + ra);    ra += N_NODES;
  int*   row_start= (int*)(ws + ra);    ra += N_NODES;
  int*   cursor   = (int*)(ws + ra);    ra += N_NODES;
  int*   bsum     = (int*)(ws + ra);    ra += 256;
  float* h2tab    = ws + ra;            ra += (size_t)NL * TBL * HID;
  float* wtab     = ws + ra;            ra += (size_t)NL * TBL * 128;
  unsigned short* s_bf  = (unsigned short*)(ws + ra); ra += (size_t)N_NODES * C / 2;
  unsigned short* v_bf4 = (unsigned short*)(ws + ra); ra += (size_t)N_NODES * C * 2; // 4 ushorts/elem
  size_t req_sorted = ra * 4;

  // --- region B (fallback atomic path, aliases region A) ---
  size_t rb = off;
  float* agg_sf = ws + rb; rb += (size_t)N_NODES * C;
  float* agg_sg = ws + rb; rb += (size_t)N_NODES * C;
  float* agg_v  = ws + rb; rb += (size_t)N_NODES * C * 3;

  dim3 b256(256);
  const int gE  = (N_EDGES + 255) / 256;
  const int gNC = (N_NODES * C + 255) / 256;
  const int gN  = (N_NODES + 255) / 256;

  if (ws_size >= req_sorted) {
    hipMemsetAsync(counts, 0, N_NODES * sizeof(int), stream);
    hipMemsetAsync(cursor, 0, N_NODES * sizeof(int), stream);
    hipMemsetAsync(d_out, 0, NG * sizeof(float), stream);
    k_node_init<<<gNC, b256, 0, stream>>>(species, emb, s, s_bf);
    k_hist<<<gE, b256, 0, stream>>>(ei, counts);
    k_scanA<<<NBLK_N, b256, 0, stream>>>(counts, bsum);
    k_scanB<<<1, b256, 0, stream>>>(bsum);
    k_scanC<<<NBLK_N, b256, 0, stream>>>(counts, bsum, row_start);
    k_geom_scatter<<<gE, b256, 0, stream>>>(pos, ei, row_start, cursor, rec);
    k_table_h<<<(NL*TBL)/256, b256, 0, stream>>>(freqs, rW1, rb1, rW2, rb2, h2tab);
    k_table_w<<<(NL*TBL*16)/256, b256, 0, stream>>>(h2tab, rW3, rb3, wtab);

    // ---- layer 0 (v == 0: no v gather; apply writes v directly) ----
    hipMemsetAsync(bn_sums, 0, 96 * sizeof(double), stream);
    k_agg_update<false><<<(N_NODES*C)/256, b256, 0, stream>>>(
        wtab, rec, row_start, counts, s_bf, v_bf4,
        Wss, bss, Wvv, s_new, v_new);
    k_bn_stats<<<BN_BLOCKS, b256, 0, stream>>>(s_new, v_new, bn_sums);
    k_apply<true, false><<<gNC, b256, 0, stream>>>(s_new, v_new, bn_sums,
        bn_gs, bn_gv, bn_bs, s, v, s_bf, v_bf4,
        species, batch, W_out, b_out, atom_ref, (float*)d_out);

    // ---- layer 1 (full path; apply fuses readout) ----
    hipMemsetAsync(bn_sums, 0, 96 * sizeof(double), stream);
    k_agg_update<true><<<(N_NODES*C)/256, b256, 0, stream>>>(
        wtab + (size_t)TBL * 128, rec, row_start, counts, s_bf, v_bf4,
        Wss + C*C, bss + C, Wvv + C*C, s_new, v_new);
    k_bn_stats<<<BN_BLOCKS, b256, 0, stream>>>(s_new, v_new, bn_sums);
    k_apply<false, true><<<gNC, b256, 0, stream>>>(s_new, v_new, bn_sums,
        bn_gs + C, bn_gv + C, bn_bs + C, s, v, s_bf, v_bf4,
        species, batch, W_out, b_out, atom_ref, (float*)d_out);
  } else {
    hipMemsetAsync(v, 0, (size_t)N_NODES * C * 3 * sizeof(float), stream);
    k_node_init<<<gNC, b256, 0, stream>>>(species, emb, s, (unsigned short*)(ws + off));
    k_edge_geom<<<gE, b256, 0, stream>>>(pos, ei, freqs, basis, Y1);
    for (int l = 0; l < NL; l++) {
      hipMemsetAsync(agg_sf, 0, (size_t)N_NODES * 5 * C * sizeof(float), stream);
      hipMemsetAsync(bn_sums, 0, 96 * sizeof(double), stream);
      k_edge_msg_fb<<<gE, b256, 0, stream>>>(basis, Y1, ei, s, v,
          rW1 + l*NB*HID, rb1 + l*HID, rW2 + l*HID*HID, rb2 + l*HID,
          rW3 + l*HID*4*C, rb3 + l*4*C, agg_sf, agg_sg, agg_v);
      k_node_update_fb<<<(N_NODES*C)/256, b256, 0, stream>>>(agg_sf, agg_sg, agg_v,
          Wss + l*C*C, bss + l*C, Wvv + l*C*C, s_new, v_new, bn_sums);
      k_bn_scales_fb<<<1, 64, 0, stream>>>(bn_sums, bn_gs + l*C, bn_gv + l*C, scales);
      k_apply_fb<<<gNC, b256, 0, stream>>>(s_new, v_new, scales, bn_bs + l*C, s, v);
    }
    hipMemsetAsync(d_out, 0, NG * sizeof(float), stream);
    k_readout_fb<<<gN, b256, 0, stream>>>(s, species, batch, W_out, b_out, atom_ref, (float*)d_out);
  }
}

// Round 16
// 295.995 us; speedup vs baseline: 2.2628x; 2.2628x over previous
//
#include <hip/hip_runtime.h>
#include <math.h>

#define N_NODES 50000
#define N_EDGES 400000
#define C 32
#define NB 8
#define HID 64
#define NL 2
#define NG 64
#define RMAXF 5.0f
#define EPSF 1e-5f
#define TBL 4096
#define BN_BLOCKS 512
#define NBLK_N ((N_NODES + 255) / 256)   // 196

__device__ __forceinline__ float silu_f(float x) { return x / (1.0f + __expf(-x)); }
__device__ __forceinline__ float sigmoid_f(float x) { return 1.0f / (1.0f + __expf(-x)); }
__device__ __forceinline__ void atomAddF(float* p, float val) {
  __hip_atomic_fetch_add(p, val, __ATOMIC_RELAXED, __HIP_MEMORY_SCOPE_AGENT);
}
__device__ __forceinline__ void atomAddD(double* p, double val) {
  __hip_atomic_fetch_add(p, val, __ATOMIC_RELAXED, __HIP_MEMORY_SCOPE_AGENT);
}
__device__ __forceinline__ unsigned short bf16_rne(float f) {
  unsigned u = __float_as_uint(f);
  return (unsigned short)((u + 0x7FFFu + ((u >> 16) & 1u)) >> 16);
}
__device__ __forceinline__ float bfu(unsigned short u) {
  return __uint_as_float(((unsigned)u) << 16);
}

// ---------------- fb-only edge geometry (with basis) ----------------
__global__ __launch_bounds__(256) void k_edge_geom(
    const float* __restrict__ pos, const int* __restrict__ ei,
    const float* __restrict__ freqs,
    float* __restrict__ basis, float* __restrict__ Y1)
{
  int e = blockIdx.x * 256 + threadIdx.x;
  if (e >= N_EDGES) return;
  int s = ei[e], d = ei[N_EDGES + e];
  float vx = pos[d*3+0] - pos[s*3+0];
  float vy = pos[d*3+1] - pos[s*3+1];
  float vz = pos[d*3+2] - pos[s*3+2];
  float dist = sqrtf(vx*vx + vy*vy + vz*vz);
  float invd = 1.0f / fmaxf(dist, 1e-9f);
  Y1[e*3+0] = vx*invd; Y1[e*3+1] = vy*invd; Y1[e*3+2] = vz*invd;
  float x = fminf(fmaxf(dist * (1.0f/RMAXF), 0.0f), 1.0f);
  float x2 = x*x, x3 = x2*x;
  float cut = 1.0f - x3 * (10.0f - 15.0f*x + 6.0f*x2);
  if (dist > RMAXF) cut = 0.0f;
  float rinv = cut / fmaxf(dist, 1e-6f);
  #pragma unroll
  for (int k = 0; k < NB; k++)
    basis[e*NB + k] = sinf(freqs[k] * dist) * rinv;
}

// ---------------- node init: s fp32 + s_bf bf16 ----------------
__global__ __launch_bounds__(256) void k_node_init(
    const int* __restrict__ species, const float* __restrict__ emb,
    float* __restrict__ s, unsigned short* __restrict__ s_bf)
{
  int i = blockIdx.x * 256 + threadIdx.x;
  if (i >= N_NODES * C) return;
  int n = i >> 5, c = i & 31;
  float x = emb[species[n]*C + c];
  s[i] = x;
  s_bf[i] = bf16_rne(x);
}

// ---------------- CSR build ----------------
__global__ __launch_bounds__(256) void k_hist(const int* __restrict__ ei, int* __restrict__ counts)
{
  int e = blockIdx.x * 256 + threadIdx.x;
  if (e >= N_EDGES) return;
  atomicAdd(&counts[ei[N_EDGES + e]], 1);
}

__global__ __launch_bounds__(256) void k_scanA(const int* __restrict__ counts, int* __restrict__ bsum)
{
  __shared__ int sh[256];
  int i = blockIdx.x * 256 + threadIdx.x;
  int x = (i < N_NODES) ? counts[i] : 0;
  sh[threadIdx.x] = x;
  __syncthreads();
  for (int off = 128; off > 0; off >>= 1) {
    if (threadIdx.x < off) sh[threadIdx.x] += sh[threadIdx.x + off];
    __syncthreads();
  }
  if (threadIdx.x == 0) bsum[blockIdx.x] = sh[0];
}

__global__ __launch_bounds__(256) void k_scanB(int* __restrict__ bsum)
{
  __shared__ int sh[256];
  int tid = threadIdx.x;
  int x = (tid < NBLK_N) ? bsum[tid] : 0;
  sh[tid] = x;
  __syncthreads();
  for (int off = 1; off < 256; off <<= 1) {
    int y = (tid >= off) ? sh[tid - off] : 0;
    __syncthreads();
    sh[tid] += y;
    __syncthreads();
  }
  if (tid < NBLK_N) bsum[tid] = sh[tid] - x;   // exclusive
}

__global__ __launch_bounds__(256) void k_scanC(const int* __restrict__ counts,
                                               const int* __restrict__ bsum,
                                               int* __restrict__ row_start)
{
  __shared__ int sh[256];
  int i = blockIdx.x * 256 + threadIdx.x;
  int x = (i < N_NODES) ? counts[i] : 0;
  sh[threadIdx.x] = x;
  __syncthreads();
  for (int off = 1; off < 256; off <<= 1) {
    int y = (threadIdx.x >= off) ? sh[threadIdx.x - off] : 0;
    __syncthreads();
    sh[threadIdx.x] += y;
    __syncthreads();
  }
  if (i < N_NODES) row_start[i] = bsum[blockIdx.x] + sh[threadIdx.x] - x; // exclusive
}

// ---------------- fused geometry + scatter into packed 32B records ----------------
__global__ __launch_bounds__(256) void k_geom_scatter(
    const float* __restrict__ pos, const int* __restrict__ ei,
    const int* __restrict__ row_start, int* __restrict__ cursor,
    float* __restrict__ rec)
{
  int e = blockIdx.x * 256 + threadIdx.x;
  if (e >= N_EDGES) return;
  int s = ei[e], d = ei[N_EDGES + e];
  float vx = pos[d*3+0] - pos[s*3+0];
  float vy = pos[d*3+1] - pos[s*3+1];
  float vz = pos[d*3+2] - pos[s*3+2];
  float dist = sqrtf(vx*vx + vy*vy + vz*vz);
  float invd = 1.0f / fmaxf(dist, 1e-9f);
  int p = row_start[d] + atomicAdd(&cursor[d], 1);
  float* rp = rec + (size_t)p * 8;
  float4 r0; r0.x = dist; r0.y = __int_as_float(s); r0.z = vx*invd; r0.w = vy*invd;
  *(float4*)rp = r0;
  rp[4] = vz*invd;
}

// ---------------- radial-MLP tabulation ----------------
__global__ __launch_bounds__(256) void k_table_h(
    const float* __restrict__ freqs,
    const float* __restrict__ rW1, const float* __restrict__ rb1,
    const float* __restrict__ rW2, const float* __restrict__ rb2,
    float* __restrict__ h2tab)                 // [NL*TBL*HID]
{
  int idx = blockIdx.x * 256 + threadIdx.x;    // [NL*TBL]
  if (idx >= NL * TBL) return;
  int l = idx / TBL, i = idx - l * TBL;
  float d = (float)i * (RMAXF / (float)(TBL - 1));
  float x = fminf(fmaxf(d * (1.0f/RMAXF), 0.0f), 1.0f);
  float x2 = x*x, x3 = x2*x;
  float cut = 1.0f - x3 * (10.0f - 15.0f*x + 6.0f*x2);
  float rinv = cut / fmaxf(d, 1e-6f);
  float bas[NB];
  #pragma unroll
  for (int k = 0; k < NB; k++) bas[k] = sinf(freqs[k] * d) * rinv;

  const float* W1 = rW1 + l*NB*HID;
  const float* B1 = rb1 + l*HID;
  const float* W2 = rW2 + l*HID*HID;
  const float* B2 = rb2 + l*HID;

  float h2[HID];
  #pragma unroll
  for (int j = 0; j < HID; j++) h2[j] = B2[j];
  #pragma unroll 2
  for (int k = 0; k < HID; k++) {
    float t = B1[k];
    #pragma unroll
    for (int b = 0; b < NB; b++) t = fmaf(bas[b], W1[b*HID + k], t);
    float h1k = silu_f(t);
    const float* r = W2 + k*HID;
    #pragma unroll
    for (int j = 0; j < HID; j++) h2[j] = fmaf(h1k, r[j], h2[j]);
  }
  float* out = h2tab + (size_t)idx * HID;
  #pragma unroll
  for (int j = 0; j < HID; j++) out[j] = silu_f(h2[j]);
}

__global__ __launch_bounds__(256) void k_table_w(
    const float* __restrict__ h2tab,
    const float* __restrict__ rW3, const float* __restrict__ rb3,
    float* __restrict__ wtab)                  // [NL*TBL*128]
{
  int idx = blockIdx.x * 256 + threadIdx.x;    // [NL*TBL*16]
  if (idx >= NL * TBL * 16) return;
  int chunk = idx & 15;
  int row   = idx >> 4;                        // l*TBL + i
  int l     = row / TBL;
  const float* h2 = h2tab + (size_t)row * HID;
  const float* W3 = rW3 + l*HID*4*C + chunk*8;
  const float* B3 = rb3 + l*4*C + chunk*8;
  float a[8];
  #pragma unroll
  for (int ci = 0; ci < 8; ci++) a[ci] = B3[ci];
  #pragma unroll 4
  for (int k = 0; k < HID; k++) {
    float h = h2[k];
    #pragma unroll
    for (int ci = 0; ci < 8; ci++) a[ci] = fmaf(h, W3[k*4*C + ci], a[ci]);
  }
  float* out = wtab + (size_t)row * 128 + chunk*8;
  #pragma unroll
  for (int ci = 0; ci < 8; ci++) out[ci] = a[ci];
}

// ---------------- aggregate: packed records, pipelined, layer-specialized ---------
template<bool HAS_V>
__global__ __launch_bounds__(256) void k_agg_update(
    const float* __restrict__ tb,              // this layer's wtab [TBL][128]
    const float* __restrict__ rec,
    const int* __restrict__ row_start, const int* __restrict__ counts,
    const unsigned short* __restrict__ s_bf, const unsigned short* __restrict__ v_bf4,
    const float* __restrict__ Wss, const float* __restrict__ bss,
    const float* __restrict__ Wvv,
    float* __restrict__ s_new, float* __restrict__ v_new)
{
  int t = blockIdx.x * 256 + threadIdx.x;
  int n = t >> 5;
  int c = t & 31;

  const float SCALE = (float)(TBL - 1) / RMAXF;
  float asf = 0.0f, asg = 0.0f, av0 = 0.0f, av1 = 0.0f, av2 = 0.0f;
  int beg = row_start[n], cnt = counts[n];

  if (cnt > 0) {
    int last = beg + cnt - 1;
    int pA = beg, pB = (beg + 1 < last) ? beg + 1 : last;
    float4 rA = *(const float4*)(rec + (size_t)pA * 8);
    float  zA = rec[(size_t)pA * 8 + 4];
    float4 rB = *(const float4*)(rec + (size_t)pB * 8);
    float  zB = rec[(size_t)pB * 8 + 4];

    for (int i = 0; i < cnt; i += 2) {
      int pA2 = beg + i + 2; pA2 = pA2 < last ? pA2 : last;
      int pB2 = beg + i + 3; pB2 = pB2 < last ? pB2 : last;
      float4 rA_n = *(const float4*)(rec + (size_t)pA2 * 8);
      float  zA_n = rec[(size_t)pA2 * 8 + 4];
      float4 rB_n = *(const float4*)(rec + (size_t)pB2 * 8);
      float  zB_n = rec[(size_t)pB2 * 8 + 4];

      float validB = (i + 1 < cnt) ? 1.0f : 0.0f;
      float dA = rA.x;  int srcA = __float_as_int(rA.y);
      float yA0 = rA.z, yA1 = rA.w, yA2 = zA;
      float dB = rB.x;  int srcB = __float_as_int(rB.y);
      float yB0 = rB.z, yB1 = rB.w, yB2 = zB;

      float xsA = bfu(s_bf[srcA*C + c]);
      float xsB = bfu(s_bf[srcB*C + c]);
      float xvA0 = 0.0f, xvA1 = 0.0f, xvA2 = 0.0f;
      float xvB0 = 0.0f, xvB1 = 0.0f, xvB2 = 0.0f;
      if (HAS_V) {
        ushort4 a4 = *(const ushort4*)(v_bf4 + (size_t)(srcA*C + c)*4);
        ushort4 b4 = *(const ushort4*)(v_bf4 + (size_t)(srcB*C + c)*4);
        xvA0 = bfu(a4.x); xvA1 = bfu(a4.y); xvA2 = bfu(a4.z);
        xvB0 = bfu(b4.x); xvB1 = bfu(b4.y); xvB2 = bfu(b4.z);
      }

      float tsA = fminf(dA, RMAXF) * SCALE;
      int t0A = (int)tsA; t0A = t0A > TBL-2 ? TBL-2 : t0A;
      float frA = tsA - (float)t0A;
      float tsB = fminf(dB, RMAXF) * SCALE;
      int t0B = (int)tsB; t0B = t0B > TBL-2 ? TBL-2 : t0B;
      float frB = tsB - (float)t0B;

      const float* rtA0 = tb + (size_t)t0A * 128 + c;
      const float* rtA1 = rtA0 + 128;
      const float* rtB0 = tb + (size_t)t0B * 128 + c;
      const float* rtB1 = rtB0 + 128;

      float w1A = fmaf(frA, rtA1[0]  - rtA0[0],  rtA0[0]);
      float w3A = fmaf(frA, rtA1[64] - rtA0[64], rtA0[64]);
      float w1B = validB * fmaf(frB, rtB1[0]  - rtB0[0],  rtB0[0]);
      float w3B = validB * fmaf(frB, rtB1[64] - rtB0[64], rtB0[64]);

      asf = fmaf(w1A, xsA, asf);
      float w3xsA = w3A * xsA;
      asf = fmaf(w1B, xsB, asf);
      float w3xsB = w3B * xsB;

      if (HAS_V) {
        float w2A = fmaf(frA, rtA1[32] - rtA0[32], rtA0[32]);
        float w4A = fmaf(frA, rtA1[96] - rtA0[96], rtA0[96]);
        float w2B = validB * fmaf(frB, rtB1[32] - rtB0[32], rtB0[32]);
        float w4B = validB * fmaf(frB, rtB1[96] - rtB0[96], rtB0[96]);
        asg = fmaf(w2A, xvA0*yA0 + xvA1*yA1 + xvA2*yA2, asg);
        asg = fmaf(w2B, xvB0*yB0 + xvB1*yB1 + xvB2*yB2, asg);
        av0 += fmaf(w3xsA, yA0, w4A*xvA0) + fmaf(w3xsB, yB0, w4B*xvB0);
        av1 += fmaf(w3xsA, yA1, w4A*xvA1) + fmaf(w3xsB, yB1, w4B*xvB1);
        av2 += fmaf(w3xsA, yA2, w4A*xvA2) + fmaf(w3xsB, yB2, w4B*xvB2);
      } else {
        av0 += fmaf(w3xsA, yA0, w3xsB * yB0);
        av1 += fmaf(w3xsA, yA1, w3xsB * yB1);
        av2 += fmaf(w3xsA, yA2, w3xsB * yB2);
      }

      rA = rA_n; zA = zA_n; rB = rB_n; zB = zB_n;
    }
  }

  float sgv  = silu_f(asf);
  float gate = sigmoid_f(asg);               // asg==0 for layer 0 -> 0.5, matches ref
  float vg0 = gate*av0, vg1 = gate*av1, vg2 = gate*av2;

  // self-interaction: 32x32 mix via lane broadcast
  float sn = bss[c];
  float vm0 = 0.0f, vm1 = 0.0f, vm2 = 0.0f;
  #pragma unroll
  for (int k = 0; k < C; k++) {
    float a  = __shfl(sgv, k, 32);
    sn = fmaf(a, Wss[k*C + c], sn);
    float wv = Wvv[k*C + c];
    vm0 = fmaf(__shfl(vg0, k, 32), wv, vm0);
    vm1 = fmaf(__shfl(vg1, k, 32), wv, vm1);
    vm2 = fmaf(__shfl(vg2, k, 32), wv, vm2);
  }

  s_new[n*C + c] = sn;
  float* vo = v_new + (size_t)(n*C + c)*3;
  vo[0] = vm0; vo[1] = vm1; vo[2] = vm2;
}

// ---------------- BN stats (grid-stride, register accumulation) ----------------
__global__ __launch_bounds__(256) void k_bn_stats(
    const float* __restrict__ s_new, const float* __restrict__ v_new,
    double* __restrict__ bn_sums)
{
  __shared__ float lacc[3*C];
  if (threadIdx.x < 3*C) lacc[threadIdx.x] = 0.0f;
  __syncthreads();
  int c = threadIdx.x & 31;
  float r1 = 0.0f, r2 = 0.0f, r3 = 0.0f;
  const int NC = N_NODES * C;
  for (int i = blockIdx.x * 256 + threadIdx.x; i < NC; i += BN_BLOCKS * 256) {
    float sn = s_new[i];
    const float* vp = v_new + (size_t)i * 3;
    r1 += sn;
    r2 += sn * sn;
    r3 += vp[0]*vp[0] + vp[1]*vp[1] + vp[2]*vp[2];
  }
  atomicAdd(&lacc[c],       r1);
  atomicAdd(&lacc[C + c],   r2);
  atomicAdd(&lacc[2*C + c], r3);
  __syncthreads();
  if (threadIdx.x < 3*C) atomAddD(&bn_sums[threadIdx.x], (double)lacc[threadIdx.x]);
}

// ---------------- apply BN + residual + bf16 mirror; FIRST: v write-direct --------
template<bool FIRST>
__global__ __launch_bounds__(256) void k_apply(
    const float* __restrict__ s_new, const float* __restrict__ v_new,
    const double* __restrict__ bn_sums,
    const float* __restrict__ gs, const float* __restrict__ gv,
    const float* __restrict__ bn_bs,
    float* __restrict__ s, float* __restrict__ v,
    unsigned short* __restrict__ s_bf, unsigned short* __restrict__ v_bf4)
{
  int i = blockIdx.x * 256 + threadIdx.x;
  if (i >= N_NODES * C) return;
  int c = i & 31;
  double S1 = bn_sums[c], S2 = bn_sums[C + c], VN = bn_sums[2*C + c];
  float mu  = (float)(S1 / (double)N_NODES);
  float var = (float)(S2 / (double)N_NODES) - mu*mu;
  float vn2 = (float)(VN / (3.0 * (double)N_NODES));
  float ssc = gs[c] / sqrtf(var + EPSF);
  float vsc = gv[c] / sqrtf(vn2 + EPSF);

  float sv = s[i] + (s_new[i] - mu) * ssc + bn_bs[c];
  s[i] = sv;
  s_bf[i] = bf16_rne(sv);
  float* vp = v + (size_t)i*3;
  const float* vn = v_new + (size_t)i*3;
  ushort4 vb;
  float vv0 = (FIRST ? 0.0f : vp[0]) + vn[0] * vsc;
  float vv1 = (FIRST ? 0.0f : vp[1]) + vn[1] * vsc;
  float vv2 = (FIRST ? 0.0f : vp[2]) + vn[2] * vsc;
  vp[0] = vv0; vp[1] = vv1; vp[2] = vv2;
  vb.x = bf16_rne(vv0); vb.y = bf16_rne(vv1); vb.z = bf16_rne(vv2); vb.w = 0;
  *(ushort4*)(v_bf4 + (size_t)i*4) = vb;
}

// ---------------- readout (LDS per-graph accumulate; batch sorted -> ~2 global
//                  atomics per block, NOT 50K direct atomics: r15 lesson) ---------
__global__ __launch_bounds__(256) void k_readout(
    const float* __restrict__ s, const int* __restrict__ species,
    const int* __restrict__ batch,
    const float* __restrict__ W_out, const float* __restrict__ b_out,
    const float* __restrict__ atom_ref, float* __restrict__ out)
{
  __shared__ float acc[NG];
  if (threadIdx.x < NG) acc[threadIdx.x] = 0.0f;
  __syncthreads();
  int n = blockIdx.x * 256 + threadIdx.x;
  if (n < N_NODES) {
    float e = b_out[0] + atom_ref[species[n]];
    #pragma unroll
    for (int c = 0; c < C; c++) e = fmaf(s[n*C + c], W_out[c], e);
    atomicAdd(&acc[batch[n]], e);
  }
  __syncthreads();
  if (threadIdx.x < NG) {
    float a = acc[threadIdx.x];
    if (a != 0.0f) atomAddF(&out[threadIdx.x], a);
  }
}

// ================= FALLBACK (atomic path, used only if ws too small) ==========
__global__ __launch_bounds__(256) void k_edge_msg_fb(
    const float* __restrict__ basis, const float* __restrict__ Y1,
    const int* __restrict__ ei,
    const float* __restrict__ s, const float* __restrict__ v,
    const float* __restrict__ rW1, const float* __restrict__ rb1,
    const float* __restrict__ rW2, const float* __restrict__ rb2,
    const float* __restrict__ rW3, const float* __restrict__ rb3,
    float* __restrict__ agg_sf, float* __restrict__ agg_sg, float* __restrict__ agg_v)
{
  int e = blockIdx.x * 256 + threadIdx.x;
  if (e >= N_EDGES) return;
  int src = ei[e], dst = ei[N_EDGES + e];
  const float4 b0 = *(const float4*)(basis + (size_t)e*NB);
  const float4 b1 = *(const float4*)(basis + (size_t)e*NB + 4);
  float bas[NB] = {b0.x, b0.y, b0.z, b0.w, b1.x, b1.y, b1.z, b1.w};
  float h2[HID];
  #pragma unroll
  for (int j = 0; j < HID; j++) h2[j] = rb2[j];
  #pragma unroll 2
  for (int k = 0; k < HID; k++) {
    float t = rb1[k];
    #pragma unroll
    for (int b = 0; b < NB; b++) t = fmaf(bas[b], rW1[b*HID + k], t);
    float h1k = silu_f(t);
    const float* r = rW2 + k*HID;
    #pragma unroll
    for (int j = 0; j < HID; j++) h2[j] = fmaf(h1k, r[j], h2[j]);
  }
  #pragma unroll
  for (int j = 0; j < HID; j++) h2[j] = silu_f(h2[j]);
  float y0 = Y1[e*3+0], y1 = Y1[e*3+1], y2 = Y1[e*3+2];
  #pragma unroll 1
  for (int cb = 0; cb < 16; cb++) {
    float a[8];
    #pragma unroll
    for (int ci = 0; ci < 8; ci++) a[ci] = rb3[cb*8 + ci];
    #pragma unroll
    for (int k = 0; k < HID; k++) {
      float h = h2[k];
      #pragma unroll
      for (int ci = 0; ci < 8; ci++) a[ci] = fmaf(h, rW3[k*4*C + cb*8 + ci], a[ci]);
    }
    #pragma unroll
    for (int ci = 0; ci < 8; ci++) {
      int o = cb*8 + ci;
      int path = o >> 5;
      int c = o & 31;
      float xs = s[src*C + c];
      const float* vp = v + (size_t)(src*C + c)*3;
      float xv0 = vp[0], xv1 = vp[1], xv2 = vp[2];
      if (path == 0) {
        atomAddF(&agg_sf[dst*C + c], a[ci] * xs);
      } else if (path == 1) {
        atomAddF(&agg_sg[dst*C + c], a[ci] * (xv0*y0 + xv1*y1 + xv2*y2));
      } else if (path == 2) {
        float w3xs = a[ci] * xs;
        float* ap = agg_v + (size_t)(dst*C + c)*3;
        atomAddF(ap+0, w3xs*y0); atomAddF(ap+1, w3xs*y1); atomAddF(ap+2, w3xs*y2);
      } else {
        float* ap = agg_v + (size_t)(dst*C + c)*3;
        atomAddF(ap+0, a[ci]*xv0); atomAddF(ap+1, a[ci]*xv1); atomAddF(ap+2, a[ci]*xv2);
      }
    }
  }
}

__global__ __launch_bounds__(256) void k_node_update_fb(
    const float* __restrict__ agg_sf, const float* __restrict__ agg_sg,
    const float* __restrict__ agg_v,
    const float* __restrict__ Wss, const float* __restrict__ bss,
    const float* __restrict__ Wvv,
    float* __restrict__ s_new, float* __restrict__ v_new,
    double* __restrict__ bn_sums)
{
  __shared__ float lacc[3*C];
  int t = blockIdx.x * 256 + threadIdx.x;
  int n = t >> 5;
  int c = t & 31;
  if (threadIdx.x < 3*C) lacc[threadIdx.x] = 0.0f;
  __syncthreads();
  float asf = agg_sf[n*C + c];
  float asg = agg_sg[n*C + c];
  const float* ap = agg_v + (size_t)(n*C + c)*3;
  float av0 = ap[0], av1 = ap[1], av2 = ap[2];
  float sgv = silu_f(asf);
  float gate = sigmoid_f(asg);
  float vg0 = gate*av0, vg1 = gate*av1, vg2 = gate*av2;
  float sn = bss[c];
  float vm0 = 0.0f, vm1 = 0.0f, vm2 = 0.0f;
  #pragma unroll
  for (int k = 0; k < C; k++) {
    float a  = __shfl(sgv, k, 32);
    sn = fmaf(a, Wss[k*C + c], sn);
    float wv = Wvv[k*C + c];
    vm0 = fmaf(__shfl(vg0, k, 32), wv, vm0);
    vm1 = fmaf(__shfl(vg1, k, 32), wv, vm1);
    vm2 = fmaf(__shfl(vg2, k, 32), wv, vm2);
  }
  s_new[n*C + c] = sn;
  float* vo = v_new + (size_t)(n*C + c)*3;
  vo[0] = vm0; vo[1] = vm1; vo[2] = vm2;
  float vn2 = vm0*vm0 + vm1*vm1 + vm2*vm2;
  atomicAdd(&lacc[c], sn);
  atomicAdd(&lacc[C + c], sn*sn);
  atomicAdd(&lacc[2*C + c], vn2);
  __syncthreads();
  if (threadIdx.x < 3*C) atomAddD(&bn_sums[threadIdx.x], (double)lacc[threadIdx.x]);
}

__global__ void k_bn_scales_fb(const double* __restrict__ bn_sums,
                               const float* __restrict__ gs, const float* __restrict__ gv,
                               float* __restrict__ scales)
{
  int m = threadIdx.x;
  if (m >= C) return;
  double S1 = bn_sums[m], S2 = bn_sums[C + m], VN = bn_sums[2*C + m];
  double mu  = S1 / (double)N_NODES;
  double var = S2 / (double)N_NODES - mu*mu;
  double vn2 = VN / (3.0 * (double)N_NODES);
  scales[m]       = (float)mu;
  scales[C + m]   = gs[m] / sqrtf((float)var + EPSF);
  scales[2*C + m] = gv[m] / sqrtf((float)vn2 + EPSF);
}

__global__ __launch_bounds__(256) void k_apply_fb(
    const float* __restrict__ s_new, const float* __restrict__ v_new,
    const float* __restrict__ scales, const float* __restrict__ bn_bs,
    float* __restrict__ s, float* __restrict__ v)
{
  int i = blockIdx.x * 256 + threadIdx.x;
  if (i >= N_NODES * C) return;
  int c = i & 31;
  s[i] += (s_new[i] - scales[c]) * scales[C + c] + bn_bs[c];
  float vs = scales[2*C + c];
  v[(size_t)i*3+0] += v_new[(size_t)i*3+0] * vs;
  v[(size_t)i*3+1] += v_new[(size_t)i*3+1] * vs;
  v[(size_t)i*3+2] += v_new[(size_t)i*3+2] * vs;
}

extern "C" void kernel_launch(void* const* d_in, const int* in_sizes, int n_in,
                              void* d_out, int out_size, void* d_ws, size_t ws_size,
                              hipStream_t stream)
{
  const int*   species  = (const int*)  d_in[0];
  const float* pos      = (const float*)d_in[1];
  const int*   ei       = (const int*)  d_in[2];
  const int*   batch    = (const int*)  d_in[3];
  const float* emb      = (const float*)d_in[4];
  const float* freqs    = (const float*)d_in[5];
  const float* rW1      = (const float*)d_in[6];
  const float* rb1      = (const float*)d_in[7];
  const float* rW2      = (const float*)d_in[8];
  const float* rb2      = (const float*)d_in[9];
  const float* rW3      = (const float*)d_in[10];
  const float* rb3      = (const float*)d_in[11];
  const float* Wss      = (const float*)d_in[12];
  const float* bss      = (const float*)d_in[13];
  const float* Wvv      = (const float*)d_in[14];
  const float* bn_gs    = (const float*)d_in[15];
  const float* bn_bs    = (const float*)d_in[16];
  const float* bn_gv    = (const float*)d_in[17];
  const float* W_out    = (const float*)d_in[18];
  const float* b_out    = (const float*)d_in[19];
  const float* atom_ref = (const float*)d_in[20];

  float* ws = (float*)d_ws;
  size_t off = 0;
  float* basis  = ws + off; off += (size_t)N_EDGES * NB;     // fb path only
  float* Y1     = ws + off; off += (size_t)N_EDGES * 3;      // fb path only
  float* s      = ws + off; off += (size_t)N_NODES * C;
  float* v      = ws + off; off += (size_t)N_NODES * C * 3;
  float* s_new  = ws + off; off += (size_t)N_NODES * C;
  float* v_new  = ws + off; off += (size_t)N_NODES * C * 3;
  double* bn_sums = (double*)(ws + off); off += 192;
  float* scales = ws + off; off += 96;

  // --- region A (sorted + table path) ---
  size_t ra = off;
  float* rec      = ws + ra;            ra += (size_t)N_EDGES * 8;
  int*   counts   = (int*)(ws + ra);    ra += N_NODES;
  int*   row_start= (int*)(ws + ra);    ra += N_NODES;
  int*   cursor   = (int*)(ws + ra);    ra += N_NODES;
  int*   bsum     = (int*)(ws + ra);    ra += 256;
  float* h2tab    = ws + ra;            ra += (size_t)NL * TBL * HID;
  float* wtab     = ws + ra;            ra += (size_t)NL * TBL * 128;
  unsigned short* s_bf  = (unsigned short*)(ws + ra); ra += (size_t)N_NODES * C / 2;
  unsigned short* v_bf4 = (unsigned short*)(ws + ra); ra += (size_t)N_NODES * C * 2; // 4 ushorts/elem
  size_t req_sorted = ra * 4;

  // --- region B (fallback atomic path, aliases region A) ---
  size_t rb = off;
  float* agg_sf = ws + rb; rb += (size_t)N_NODES * C;
  float* agg_sg = ws + rb; rb += (size_t)N_NODES * C;
  float* agg_v  = ws + rb; rb += (size_t)N_NODES * C * 3;

  dim3 b256(256);
  const int gE  = (N_EDGES + 255) / 256;
  const int gNC = (N_NODES * C + 255) / 256;
  const int gN  = (N_NODES + 255) / 256;

  if (ws_size >= req_sorted) {
    hipMemsetAsync(counts, 0, N_NODES * sizeof(int), stream);
    hipMemsetAsync(cursor, 0, N_NODES * sizeof(int), stream);
    hipMemsetAsync(d_out, 0, NG * sizeof(float), stream);
    k_node_init<<<gNC, b256, 0, stream>>>(species, emb, s, s_bf);
    k_hist<<<gE, b256, 0, stream>>>(ei, counts);
    k_scanA<<<NBLK_N, b256, 0, stream>>>(counts, bsum);
    k_scanB<<<1, b256, 0, stream>>>(bsum);
    k_scanC<<<NBLK_N, b256, 0, stream>>>(counts, bsum, row_start);
    k_geom_scatter<<<gE, b256, 0, stream>>>(pos, ei, row_start, cursor, rec);
    k_table_h<<<(NL*TBL)/256, b256, 0, stream>>>(freqs, rW1, rb1, rW2, rb2, h2tab);
    k_table_w<<<(NL*TBL*16)/256, b256, 0, stream>>>(h2tab, rW3, rb3, wtab);

    // ---- layer 0 (v == 0: no v gather; apply writes v directly) ----
    hipMemsetAsync(bn_sums, 0, 96 * sizeof(double), stream);
    k_agg_update<false><<<(N_NODES*C)/256, b256, 0, stream>>>(
        wtab, rec, row_start, counts, s_bf, v_bf4,
        Wss, bss, Wvv, s_new, v_new);
    k_bn_stats<<<BN_BLOCKS, b256, 0, stream>>>(s_new, v_new, bn_sums);
    k_apply<true><<<gNC, b256, 0, stream>>>(s_new, v_new, bn_sums,
        bn_gs, bn_gv, bn_bs, s, v, s_bf, v_bf4);

    // ---- layer 1 (full path) ----
    hipMemsetAsync(bn_sums, 0, 96 * sizeof(double), stream);
    k_agg_update<true><<<(N_NODES*C)/256, b256, 0, stream>>>(
        wtab + (size_t)TBL * 128, rec, row_start, counts, s_bf, v_bf4,
        Wss + C*C, bss + C, Wvv + C*C, s_new, v_new);
    k_bn_stats<<<BN_BLOCKS, b256, 0, stream>>>(s_new, v_new, bn_sums);
    k_apply<false><<<gNC, b256, 0, stream>>>(s_new, v_new, bn_sums,
        bn_gs + C, bn_gv + C, bn_bs + C, s, v, s_bf, v_bf4);

    k_readout<<<gN, b256, 0, stream>>>(s, species, batch, W_out, b_out, atom_ref, (float*)d_out);
  } else {
    hipMemsetAsync(v, 0, (size_t)N_NODES * C * 3 * sizeof(float), stream);
    k_node_init<<<gNC, b256, 0, stream>>>(species, emb, s, (unsigned short*)(ws + off));
    k_edge_geom<<<gE, b256, 0, stream>>>(pos, ei, freqs, basis, Y1);
    for (int l = 0; l < NL; l++) {
      hipMemsetAsync(agg_sf, 0, (size_t)N_NODES * 5 * C * sizeof(float), stream);
      hipMemsetAsync(bn_sums, 0, 96 * sizeof(double), stream);
      k_edge_msg_fb<<<gE, b256, 0, stream>>>(basis, Y1, ei, s, v,
          rW1 + l*NB*HID, rb1 + l*HID, rW2 + l*HID*HID, rb2 + l*HID,
          rW3 + l*HID*4*C, rb3 + l*4*C, agg_sf, agg_sg, agg_v);
      k_node_update_fb<<<(N_NODES*C)/256, b256, 0, stream>>>(agg_sf, agg_sg, agg_v,
          Wss + l*C*C, bss + l*C, Wvv + l*C*C, s_new, v_new, bn_sums);
      k_bn_scales_fb<<<1, 64, 0, stream>>>(bn_sums, bn_gs + l*C, bn_gv + l*C, scales);
      k_apply_fb<<<gNC, b256, 0, stream>>>(s_new, v_new, scales, bn_bs + l*C, s, v);
    }
    hipMemsetAsync(d_out, 0, NG * sizeof(float), stream);
    k_readout<<<gN, b256, 0, stream>>>(s, species, batch, W_out, b_out, atom_ref, (float*)d_out);
  }
}

// Round 17
// 294.453 us; speedup vs baseline: 2.2746x; 1.0052x over previous
//
#include <hip/hip_runtime.h>
#include <math.h>

#define N_NODES 50000
#define N_EDGES 400000
#define C 32
#define NB 8
#define HID 64
#define NL 2
#define NG 64
#define RMAXF 5.0f
#define EPSF 1e-5f
#define TBL 4096
#define BN_BLOCKS 512
#define NBLK_N ((N_NODES + 255) / 256)   // 196

__device__ __forceinline__ float silu_f(float x) { return x / (1.0f + __expf(-x)); }
__device__ __forceinline__ float sigmoid_f(float x) { return 1.0f / (1.0f + __expf(-x)); }
__device__ __forceinline__ void atomAddF(float* p, float val) {
  __hip_atomic_fetch_add(p, val, __ATOMIC_RELAXED, __HIP_MEMORY_SCOPE_AGENT);
}
__device__ __forceinline__ void atomAddD(double* p, double val) {
  __hip_atomic_fetch_add(p, val, __ATOMIC_RELAXED, __HIP_MEMORY_SCOPE_AGENT);
}
__device__ __forceinline__ unsigned short bf16_rne(float f) {
  unsigned u = __float_as_uint(f);
  return (unsigned short)((u + 0x7FFFu + ((u >> 16) & 1u)) >> 16);
}
__device__ __forceinline__ float bfu(unsigned short u) {
  return __uint_as_float(((unsigned)u) << 16);
}

// ---------------- fb-only edge geometry (with basis) ----------------
__global__ __launch_bounds__(256) void k_edge_geom(
    const float* __restrict__ pos, const int* __restrict__ ei,
    const float* __restrict__ freqs,
    float* __restrict__ basis, float* __restrict__ Y1)
{
  int e = blockIdx.x * 256 + threadIdx.x;
  if (e >= N_EDGES) return;
  int s = ei[e], d = ei[N_EDGES + e];
  float vx = pos[d*3+0] - pos[s*3+0];
  float vy = pos[d*3+1] - pos[s*3+1];
  float vz = pos[d*3+2] - pos[s*3+2];
  float dist = sqrtf(vx*vx + vy*vy + vz*vz);
  float invd = 1.0f / fmaxf(dist, 1e-9f);
  Y1[e*3+0] = vx*invd; Y1[e*3+1] = vy*invd; Y1[e*3+2] = vz*invd;
  float x = fminf(fmaxf(dist * (1.0f/RMAXF), 0.0f), 1.0f);
  float x2 = x*x, x3 = x2*x;
  float cut = 1.0f - x3 * (10.0f - 15.0f*x + 6.0f*x2);
  if (dist > RMAXF) cut = 0.0f;
  float rinv = cut / fmaxf(dist, 1e-6f);
  #pragma unroll
  for (int k = 0; k < NB; k++)
    basis[e*NB + k] = sinf(freqs[k] * dist) * rinv;
}

// ---------------- node init: s fp32 + s_bf bf16 ----------------
__global__ __launch_bounds__(256) void k_node_init(
    const int* __restrict__ species, const float* __restrict__ emb,
    float* __restrict__ s, unsigned short* __restrict__ s_bf)
{
  int i = blockIdx.x * 256 + threadIdx.x;
  if (i >= N_NODES * C) return;
  int n = i >> 5, c = i & 31;
  float x = emb[species[n]*C + c];
  s[i] = x;
  s_bf[i] = bf16_rne(x);
}

// ---------------- CSR build ----------------
__global__ __launch_bounds__(256) void k_hist(const int* __restrict__ ei, int* __restrict__ counts)
{
  int e = blockIdx.x * 256 + threadIdx.x;
  if (e >= N_EDGES) return;
  atomicAdd(&counts[ei[N_EDGES + e]], 1);
}

__global__ __launch_bounds__(256) void k_scanA(const int* __restrict__ counts, int* __restrict__ bsum)
{
  __shared__ int sh[256];
  int i = blockIdx.x * 256 + threadIdx.x;
  int x = (i < N_NODES) ? counts[i] : 0;
  sh[threadIdx.x] = x;
  __syncthreads();
  for (int off = 128; off > 0; off >>= 1) {
    if (threadIdx.x < off) sh[threadIdx.x] += sh[threadIdx.x + off];
    __syncthreads();
  }
  if (threadIdx.x == 0) bsum[blockIdx.x] = sh[0];
}

__global__ __launch_bounds__(256) void k_scanB(int* __restrict__ bsum)
{
  __shared__ int sh[256];
  int tid = threadIdx.x;
  int x = (tid < NBLK_N) ? bsum[tid] : 0;
  sh[tid] = x;
  __syncthreads();
  for (int off = 1; off < 256; off <<= 1) {
    int y = (tid >= off) ? sh[tid - off] : 0;
    __syncthreads();
    sh[tid] += y;
    __syncthreads();
  }
  if (tid < NBLK_N) bsum[tid] = sh[tid] - x;   // exclusive
}

__global__ __launch_bounds__(256) void k_scanC(const int* __restrict__ counts,
                                               const int* __restrict__ bsum,
                                               int* __restrict__ row_start)
{
  __shared__ int sh[256];
  int i = blockIdx.x * 256 + threadIdx.x;
  int x = (i < N_NODES) ? counts[i] : 0;
  sh[threadIdx.x] = x;
  __syncthreads();
  for (int off = 1; off < 256; off <<= 1) {
    int y = (threadIdx.x >= off) ? sh[threadIdx.x - off] : 0;
    __syncthreads();
    sh[threadIdx.x] += y;
    __syncthreads();
  }
  if (i < N_NODES) row_start[i] = bsum[blockIdx.x] + sh[threadIdx.x] - x; // exclusive
}

// ---------------- fused geometry + scatter into packed 32B records ----------------
__global__ __launch_bounds__(256) void k_geom_scatter(
    const float* __restrict__ pos, const int* __restrict__ ei,
    const int* __restrict__ row_start, int* __restrict__ cursor,
    float* __restrict__ rec)
{
  int e = blockIdx.x * 256 + threadIdx.x;
  if (e >= N_EDGES) return;
  int s = ei[e], d = ei[N_EDGES + e];
  float vx = pos[d*3+0] - pos[s*3+0];
  float vy = pos[d*3+1] - pos[s*3+1];
  float vz = pos[d*3+2] - pos[s*3+2];
  float dist = sqrtf(vx*vx + vy*vy + vz*vz);
  float invd = 1.0f / fmaxf(dist, 1e-9f);
  int p = row_start[d] + atomicAdd(&cursor[d], 1);
  float* rp = rec + (size_t)p * 8;
  float4 r0; r0.x = dist; r0.y = __int_as_float(s); r0.z = vx*invd; r0.w = vy*invd;
  *(float4*)rp = r0;
  rp[4] = vz*invd;
}

// ---------------- radial-MLP tabulation ----------------
__global__ __launch_bounds__(256) void k_table_h(
    const float* __restrict__ freqs,
    const float* __restrict__ rW1, const float* __restrict__ rb1,
    const float* __restrict__ rW2, const float* __restrict__ rb2,
    float* __restrict__ h2tab)                 // [NL*TBL*HID]
{
  int idx = blockIdx.x * 256 + threadIdx.x;    // [NL*TBL]
  if (idx >= NL * TBL) return;
  int l = idx / TBL, i = idx - l * TBL;
  float d = (float)i * (RMAXF / (float)(TBL - 1));
  float x = fminf(fmaxf(d * (1.0f/RMAXF), 0.0f), 1.0f);
  float x2 = x*x, x3 = x2*x;
  float cut = 1.0f - x3 * (10.0f - 15.0f*x + 6.0f*x2);
  float rinv = cut / fmaxf(d, 1e-6f);
  float bas[NB];
  #pragma unroll
  for (int k = 0; k < NB; k++) bas[k] = sinf(freqs[k] * d) * rinv;

  const float* W1 = rW1 + l*NB*HID;
  const float* B1 = rb1 + l*HID;
  const float* W2 = rW2 + l*HID*HID;
  const float* B2 = rb2 + l*HID;

  float h2[HID];
  #pragma unroll
  for (int j = 0; j < HID; j++) h2[j] = B2[j];
  #pragma unroll 2
  for (int k = 0; k < HID; k++) {
    float t = B1[k];
    #pragma unroll
    for (int b = 0; b < NB; b++) t = fmaf(bas[b], W1[b*HID + k], t);
    float h1k = silu_f(t);
    const float* r = W2 + k*HID;
    #pragma unroll
    for (int j = 0; j < HID; j++) h2[j] = fmaf(h1k, r[j], h2[j]);
  }
  float* out = h2tab + (size_t)idx * HID;
  #pragma unroll
  for (int j = 0; j < HID; j++) out[j] = silu_f(h2[j]);
}

__global__ __launch_bounds__(256) void k_table_w(
    const float* __restrict__ h2tab,
    const float* __restrict__ rW3, const float* __restrict__ rb3,
    float* __restrict__ wtab)                  // [NL*TBL*128]
{
  int idx = blockIdx.x * 256 + threadIdx.x;    // [NL*TBL*16]
  if (idx >= NL * TBL * 16) return;
  int chunk = idx & 15;
  int row   = idx >> 4;                        // l*TBL + i
  int l     = row / TBL;
  const float* h2 = h2tab + (size_t)row * HID;
  const float* W3 = rW3 + l*HID*4*C + chunk*8;
  const float* B3 = rb3 + l*4*C + chunk*8;
  float a[8];
  #pragma unroll
  for (int ci = 0; ci < 8; ci++) a[ci] = B3[ci];
  #pragma unroll 4
  for (int k = 0; k < HID; k++) {
    float h = h2[k];
    #pragma unroll
    for (int ci = 0; ci < 8; ci++) a[ci] = fmaf(h, W3[k*4*C + ci], a[ci]);
  }
  float* out = wtab + (size_t)row * 128 + chunk*8;
  #pragma unroll
  for (int ci = 0; ci < 8; ci++) out[ci] = a[ci];
}

// ---------------- aggregate: packed records, pipelined, layer-specialized ---------
// HAS_V=false (layer 0): v==0 -> s-only gather (1 line/edge).
// HAS_V=true  (layer 1): ONE ushort4 gather carries v0,v1,v2 AND s (in .w) ->
// 4 lines/edge instead of 5 (the separate s-line fetch is eliminated).
template<bool HAS_V>
__global__ __launch_bounds__(256) void k_agg_update(
    const float* __restrict__ tb,              // this layer's wtab [TBL][128]
    const float* __restrict__ rec,
    const int* __restrict__ row_start, const int* __restrict__ counts,
    const unsigned short* __restrict__ s_bf, const unsigned short* __restrict__ v_bf4,
    const float* __restrict__ Wss, const float* __restrict__ bss,
    const float* __restrict__ Wvv,
    float* __restrict__ s_new, float* __restrict__ v_new)
{
  int t = blockIdx.x * 256 + threadIdx.x;
  int n = t >> 5;
  int c = t & 31;

  const float SCALE = (float)(TBL - 1) / RMAXF;
  float asf = 0.0f, asg = 0.0f, av0 = 0.0f, av1 = 0.0f, av2 = 0.0f;
  int beg = row_start[n], cnt = counts[n];

  if (cnt > 0) {
    int last = beg + cnt - 1;
    int pA = beg, pB = (beg + 1 < last) ? beg + 1 : last;
    float4 rA = *(const float4*)(rec + (size_t)pA * 8);
    float  zA = rec[(size_t)pA * 8 + 4];
    float4 rB = *(const float4*)(rec + (size_t)pB * 8);
    float  zB = rec[(size_t)pB * 8 + 4];

    for (int i = 0; i < cnt; i += 2) {
      int pA2 = beg + i + 2; pA2 = pA2 < last ? pA2 : last;
      int pB2 = beg + i + 3; pB2 = pB2 < last ? pB2 : last;
      float4 rA_n = *(const float4*)(rec + (size_t)pA2 * 8);
      float  zA_n = rec[(size_t)pA2 * 8 + 4];
      float4 rB_n = *(const float4*)(rec + (size_t)pB2 * 8);
      float  zB_n = rec[(size_t)pB2 * 8 + 4];

      float validB = (i + 1 < cnt) ? 1.0f : 0.0f;
      float dA = rA.x;  int srcA = __float_as_int(rA.y);
      float yA0 = rA.z, yA1 = rA.w, yA2 = zA;
      float dB = rB.x;  int srcB = __float_as_int(rB.y);
      float yB0 = rB.z, yB1 = rB.w, yB2 = zB;

      float xsA, xsB;
      float xvA0 = 0.0f, xvA1 = 0.0f, xvA2 = 0.0f;
      float xvB0 = 0.0f, xvB1 = 0.0f, xvB2 = 0.0f;
      if (HAS_V) {
        // one 8B load per edge: v in .x/.y/.z, s in .w
        ushort4 a4 = *(const ushort4*)(v_bf4 + (size_t)(srcA*C + c)*4);
        ushort4 b4 = *(const ushort4*)(v_bf4 + (size_t)(srcB*C + c)*4);
        xvA0 = bfu(a4.x); xvA1 = bfu(a4.y); xvA2 = bfu(a4.z); xsA = bfu(a4.w);
        xvB0 = bfu(b4.x); xvB1 = bfu(b4.y); xvB2 = bfu(b4.z); xsB = bfu(b4.w);
      } else {
        xsA = bfu(s_bf[srcA*C + c]);
        xsB = bfu(s_bf[srcB*C + c]);
      }

      float tsA = fminf(dA, RMAXF) * SCALE;
      int t0A = (int)tsA; t0A = t0A > TBL-2 ? TBL-2 : t0A;
      float frA = tsA - (float)t0A;
      float tsB = fminf(dB, RMAXF) * SCALE;
      int t0B = (int)tsB; t0B = t0B > TBL-2 ? TBL-2 : t0B;
      float frB = tsB - (float)t0B;

      const float* rtA0 = tb + (size_t)t0A * 128 + c;
      const float* rtA1 = rtA0 + 128;
      const float* rtB0 = tb + (size_t)t0B * 128 + c;
      const float* rtB1 = rtB0 + 128;

      float w1A = fmaf(frA, rtA1[0]  - rtA0[0],  rtA0[0]);
      float w3A = fmaf(frA, rtA1[64] - rtA0[64], rtA0[64]);
      float w1B = validB * fmaf(frB, rtB1[0]  - rtB0[0],  rtB0[0]);
      float w3B = validB * fmaf(frB, rtB1[64] - rtB0[64], rtB0[64]);

      asf = fmaf(w1A, xsA, asf);
      float w3xsA = w3A * xsA;
      asf = fmaf(w1B, xsB, asf);
      float w3xsB = w3B * xsB;

      if (HAS_V) {
        float w2A = fmaf(frA, rtA1[32] - rtA0[32], rtA0[32]);
        float w4A = fmaf(frA, rtA1[96] - rtA0[96], rtA0[96]);
        float w2B = validB * fmaf(frB, rtB1[32] - rtB0[32], rtB0[32]);
        float w4B = validB * fmaf(frB, rtB1[96] - rtB0[96], rtB0[96]);
        asg = fmaf(w2A, xvA0*yA0 + xvA1*yA1 + xvA2*yA2, asg);
        asg = fmaf(w2B, xvB0*yB0 + xvB1*yB1 + xvB2*yB2, asg);
        av0 += fmaf(w3xsA, yA0, w4A*xvA0) + fmaf(w3xsB, yB0, w4B*xvB0);
        av1 += fmaf(w3xsA, yA1, w4A*xvA1) + fmaf(w3xsB, yB1, w4B*xvB1);
        av2 += fmaf(w3xsA, yA2, w4A*xvA2) + fmaf(w3xsB, yB2, w4B*xvB2);
      } else {
        av0 += fmaf(w3xsA, yA0, w3xsB * yB0);
        av1 += fmaf(w3xsA, yA1, w3xsB * yB1);
        av2 += fmaf(w3xsA, yA2, w3xsB * yB2);
      }

      rA = rA_n; zA = zA_n; rB = rB_n; zB = zB_n;
    }
  }

  float sgv  = silu_f(asf);
  float gate = sigmoid_f(asg);               // asg==0 for layer 0 -> 0.5, matches ref
  float vg0 = gate*av0, vg1 = gate*av1, vg2 = gate*av2;

  // self-interaction: 32x32 mix via lane broadcast
  float sn = bss[c];
  float vm0 = 0.0f, vm1 = 0.0f, vm2 = 0.0f;
  #pragma unroll
  for (int k = 0; k < C; k++) {
    float a  = __shfl(sgv, k, 32);
    sn = fmaf(a, Wss[k*C + c], sn);
    float wv = Wvv[k*C + c];
    vm0 = fmaf(__shfl(vg0, k, 32), wv, vm0);
    vm1 = fmaf(__shfl(vg1, k, 32), wv, vm1);
    vm2 = fmaf(__shfl(vg2, k, 32), wv, vm2);
  }

  s_new[n*C + c] = sn;
  float* vo = v_new + (size_t)(n*C + c)*3;
  vo[0] = vm0; vo[1] = vm1; vo[2] = vm2;
}

// ---------------- BN stats (grid-stride, register accumulation) ----------------
__global__ __launch_bounds__(256) void k_bn_stats(
    const float* __restrict__ s_new, const float* __restrict__ v_new,
    double* __restrict__ bn_sums)
{
  __shared__ float lacc[3*C];
  if (threadIdx.x < 3*C) lacc[threadIdx.x] = 0.0f;
  __syncthreads();
  int c = threadIdx.x & 31;
  float r1 = 0.0f, r2 = 0.0f, r3 = 0.0f;
  const int NC = N_NODES * C;
  for (int i = blockIdx.x * 256 + threadIdx.x; i < NC; i += BN_BLOCKS * 256) {
    float sn = s_new[i];
    const float* vp = v_new + (size_t)i * 3;
    r1 += sn;
    r2 += sn * sn;
    r3 += vp[0]*vp[0] + vp[1]*vp[1] + vp[2]*vp[2];
  }
  atomicAdd(&lacc[c],       r1);
  atomicAdd(&lacc[C + c],   r2);
  atomicAdd(&lacc[2*C + c], r3);
  __syncthreads();
  if (threadIdx.x < 3*C) atomAddD(&bn_sums[threadIdx.x], (double)lacc[threadIdx.x]);
}

// ---------------- apply BN + residual + bf16 mirror; FIRST: v write-direct --------
// v_bf4.w carries bf16(s): layer-1 agg gathers s+v in one ushort4.
template<bool FIRST>
__global__ __launch_bounds__(256) void k_apply(
    const float* __restrict__ s_new, const float* __restrict__ v_new,
    const double* __restrict__ bn_sums,
    const float* __restrict__ gs, const float* __restrict__ gv,
    const float* __restrict__ bn_bs,
    float* __restrict__ s, float* __restrict__ v,
    unsigned short* __restrict__ s_bf, unsigned short* __restrict__ v_bf4)
{
  int i = blockIdx.x * 256 + threadIdx.x;
  if (i >= N_NODES * C) return;
  int c = i & 31;
  double S1 = bn_sums[c], S2 = bn_sums[C + c], VN = bn_sums[2*C + c];
  float mu  = (float)(S1 / (double)N_NODES);
  float var = (float)(S2 / (double)N_NODES) - mu*mu;
  float vn2 = (float)(VN / (3.0 * (double)N_NODES));
  float ssc = gs[c] / sqrtf(var + EPSF);
  float vsc = gv[c] / sqrtf(vn2 + EPSF);

  float sv = s[i] + (s_new[i] - mu) * ssc + bn_bs[c];
  s[i] = sv;
  s_bf[i] = bf16_rne(sv);
  float* vp = v + (size_t)i*3;
  const float* vn = v_new + (size_t)i*3;
  ushort4 vb;
  float vv0 = (FIRST ? 0.0f : vp[0]) + vn[0] * vsc;
  float vv1 = (FIRST ? 0.0f : vp[1]) + vn[1] * vsc;
  float vv2 = (FIRST ? 0.0f : vp[2]) + vn[2] * vsc;
  vp[0] = vv0; vp[1] = vv1; vp[2] = vv2;
  vb.x = bf16_rne(vv0); vb.y = bf16_rne(vv1); vb.z = bf16_rne(vv2);
  vb.w = bf16_rne(sv);                       // s rides in the pad word
  *(ushort4*)(v_bf4 + (size_t)i*4) = vb;
}

// ---------------- readout (LDS per-graph accumulate) ----------------
__global__ __launch_bounds__(256) void k_readout(
    const float* __restrict__ s, const int* __restrict__ species,
    const int* __restrict__ batch,
    const float* __restrict__ W_out, const float* __restrict__ b_out,
    const float* __restrict__ atom_ref, float* __restrict__ out)
{
  __shared__ float acc[NG];
  if (threadIdx.x < NG) acc[threadIdx.x] = 0.0f;
  __syncthreads();
  int n = blockIdx.x * 256 + threadIdx.x;
  if (n < N_NODES) {
    float e = b_out[0] + atom_ref[species[n]];
    #pragma unroll
    for (int c = 0; c < C; c++) e = fmaf(s[n*C + c], W_out[c], e);
    atomicAdd(&acc[batch[n]], e);
  }
  __syncthreads();
  if (threadIdx.x < NG) {
    float a = acc[threadIdx.x];
    if (a != 0.0f) atomAddF(&out[threadIdx.x], a);
  }
}

// ================= FALLBACK (atomic path, used only if ws too small) ==========
__global__ __launch_bounds__(256) void k_edge_msg_fb(
    const float* __restrict__ basis, const float* __restrict__ Y1,
    const int* __restrict__ ei,
    const float* __restrict__ s, const float* __restrict__ v,
    const float* __restrict__ rW1, const float* __restrict__ rb1,
    const float* __restrict__ rW2, const float* __restrict__ rb2,
    const float* __restrict__ rW3, const float* __restrict__ rb3,
    float* __restrict__ agg_sf, float* __restrict__ agg_sg, float* __restrict__ agg_v)
{
  int e = blockIdx.x * 256 + threadIdx.x;
  if (e >= N_EDGES) return;
  int src = ei[e], dst = ei[N_EDGES + e];
  const float4 b0 = *(const float4*)(basis + (size_t)e*NB);
  const float4 b1 = *(const float4*)(basis + (size_t)e*NB + 4);
  float bas[NB] = {b0.x, b0.y, b0.z, b0.w, b1.x, b1.y, b1.z, b1.w};
  float h2[HID];
  #pragma unroll
  for (int j = 0; j < HID; j++) h2[j] = rb2[j];
  #pragma unroll 2
  for (int k = 0; k < HID; k++) {
    float t = rb1[k];
    #pragma unroll
    for (int b = 0; b < NB; b++) t = fmaf(bas[b], rW1[b*HID + k], t);
    float h1k = silu_f(t);
    const float* r = rW2 + k*HID;
    #pragma unroll
    for (int j = 0; j < HID; j++) h2[j] = fmaf(h1k, r[j], h2[j]);
  }
  #pragma unroll
  for (int j = 0; j < HID; j++) h2[j] = silu_f(h2[j]);
  float y0 = Y1[e*3+0], y1 = Y1[e*3+1], y2 = Y1[e*3+2];
  #pragma unroll 1
  for (int cb = 0; cb < 16; cb++) {
    float a[8];
    #pragma unroll
    for (int ci = 0; ci < 8; ci++) a[ci] = rb3[cb*8 + ci];
    #pragma unroll
    for (int k = 0; k < HID; k++) {
      float h = h2[k];
      #pragma unroll
      for (int ci = 0; ci < 8; ci++) a[ci] = fmaf(h, rW3[k*4*C + cb*8 + ci], a[ci]);
    }
    #pragma unroll
    for (int ci = 0; ci < 8; ci++) {
      int o = cb*8 + ci;
      int path = o >> 5;
      int c = o & 31;
      float xs = s[src*C + c];
      const float* vp = v + (size_t)(src*C + c)*3;
      float xv0 = vp[0], xv1 = vp[1], xv2 = vp[2];
      if (path == 0) {
        atomAddF(&agg_sf[dst*C + c], a[ci] * xs);
      } else if (path == 1) {
        atomAddF(&agg_sg[dst*C + c], a[ci] * (xv0*y0 + xv1*y1 + xv2*y2));
      } else if (path == 2) {
        float w3xs = a[ci] * xs;
        float* ap = agg_v + (size_t)(dst*C + c)*3;
        atomAddF(ap+0, w3xs*y0); atomAddF(ap+1, w3xs*y1); atomAddF(ap+2, w3xs*y2);
      } else {
        float* ap = agg_v + (size_t)(dst*C + c)*3;
        atomAddF(ap+0, a[ci]*xv0); atomAddF(ap+1, a[ci]*xv1); atomAddF(ap+2, a[ci]*xv2);
      }
    }
  }
}

__global__ __launch_bounds__(256) void k_node_update_fb(
    const float* __restrict__ agg_sf, const float* __restrict__ agg_sg,
    const float* __restrict__ agg_v,
    const float* __restrict__ Wss, const float* __restrict__ bss,
    const float* __restrict__ Wvv,
    float* __restrict__ s_new, float* __restrict__ v_new,
    double* __restrict__ bn_sums)
{
  __shared__ float lacc[3*C];
  int t = blockIdx.x * 256 + threadIdx.x;
  int n = t >> 5;
  int c = t & 31;
  if (threadIdx.x < 3*C) lacc[threadIdx.x] = 0.0f;
  __syncthreads();
  float asf = agg_sf[n*C + c];
  float asg = agg_sg[n*C + c];
  const float* ap = agg_v + (size_t)(n*C + c)*3;
  float av0 = ap[0], av1 = ap[1], av2 = ap[2];
  float sgv = silu_f(asf);
  float gate = sigmoid_f(asg);
  float vg0 = gate*av0, vg1 = gate*av1, vg2 = gate*av2;
  float sn = bss[c];
  float vm0 = 0.0f, vm1 = 0.0f, vm2 = 0.0f;
  #pragma unroll
  for (int k = 0; k < C; k++) {
    float a  = __shfl(sgv, k, 32);
    sn = fmaf(a, Wss[k*C + c], sn);
    float wv = Wvv[k*C + c];
    vm0 = fmaf(__shfl(vg0, k, 32), wv, vm0);
    vm1 = fmaf(__shfl(vg1, k, 32), wv, vm1);
    vm2 = fmaf(__shfl(vg2, k, 32), wv, vm2);
  }
  s_new[n*C + c] = sn;
  float* vo = v_new + (size_t)(n*C + c)*3;
  vo[0] = vm0; vo[1] = vm1; vo[2] = vm2;
  float vn2 = vm0*vm0 + vm1*vm1 + vm2*vm2;
  atomicAdd(&lacc[c], sn);
  atomicAdd(&lacc[C + c], sn*sn);
  atomicAdd(&lacc[2*C + c], vn2);
  __syncthreads();
  if (threadIdx.x < 3*C) atomAddD(&bn_sums[threadIdx.x], (double)lacc[threadIdx.x]);
}

__global__ void k_bn_scales_fb(const double* __restrict__ bn_sums,
                               const float* __restrict__ gs, const float* __restrict__ gv,
                               float* __restrict__ scales)
{
  int m = threadIdx.x;
  if (m >= C) return;
  double S1 = bn_sums[m], S2 = bn_sums[C + m], VN = bn_sums[2*C + m];
  double mu  = S1 / (double)N_NODES;
  double var = S2 / (double)N_NODES - mu*mu;
  double vn2 = VN / (3.0 * (double)N_NODES);
  scales[m]       = (float)mu;
  scales[C + m]   = gs[m] / sqrtf((float)var + EPSF);
  scales[2*C + m] = gv[m] / sqrtf((float)vn2 + EPSF);
}

__global__ __launch_bounds__(256) void k_apply_fb(
    const float* __restrict__ s_new, const float* __restrict__ v_new,
    const float* __restrict__ scales, const float* __restrict__ bn_bs,
    float* __restrict__ s, float* __restrict__ v)
{
  int i = blockIdx.x * 256 + threadIdx.x;
  if (i >= N_NODES * C) return;
  int c = i & 31;
  s[i] += (s_new[i] - scales[c]) * scales[C + c] + bn_bs[c];
  float vs = scales[2*C + c];
  v[(size_t)i*3+0] += v_new[(size_t)i*3+0] * vs;
  v[(size_t)i*3+1] += v_new[(size_t)i*3+1] * vs;
  v[(size_t)i*3+2] += v_new[(size_t)i*3+2] * vs;
}

extern "C" void kernel_launch(void* const* d_in, const int* in_sizes, int n_in,
                              void* d_out, int out_size, void* d_ws, size_t ws_size,
                              hipStream_t stream)
{
  const int*   species  = (const int*)  d_in[0];
  const float* pos      = (const float*)d_in[1];
  const int*   ei       = (const int*)  d_in[2];
  const int*   batch    = (const int*)  d_in[3];
  const float* emb      = (const float*)d_in[4];
  const float* freqs    = (const float*)d_in[5];
  const float* rW1      = (const float*)d_in[6];
  const float* rb1      = (const float*)d_in[7];
  const float* rW2      = (const float*)d_in[8];
  const float* rb2      = (const float*)d_in[9];
  const float* rW3      = (const float*)d_in[10];
  const float* rb3      = (const float*)d_in[11];
  const float* Wss      = (const float*)d_in[12];
  const float* bss      = (const float*)d_in[13];
  const float* Wvv      = (const float*)d_in[14];
  const float* bn_gs    = (const float*)d_in[15];
  const float* bn_bs    = (const float*)d_in[16];
  const float* bn_gv    = (const float*)d_in[17];
  const float* W_out    = (const float*)d_in[18];
  const float* b_out    = (const float*)d_in[19];
  const float* atom_ref = (const float*)d_in[20];

  float* ws = (float*)d_ws;
  size_t off = 0;
  float* basis  = ws + off; off += (size_t)N_EDGES * NB;     // fb path only
  float* Y1     = ws + off; off += (size_t)N_EDGES * 3;      // fb path only
  float* s      = ws + off; off += (size_t)N_NODES * C;
  float* v      = ws + off; off += (size_t)N_NODES * C * 3;
  float* s_new  = ws + off; off += (size_t)N_NODES * C;
  float* v_new  = ws + off; off += (size_t)N_NODES * C * 3;
  double* bn_sums = (double*)(ws + off); off += 192;
  float* scales = ws + off; off += 96;

  // --- region A (sorted + table path) ---
  size_t ra = off;
  float* rec      = ws + ra;            ra += (size_t)N_EDGES * 8;
  int*   counts   = (int*)(ws + ra);    ra += N_NODES;
  int*   row_start= (int*)(ws + ra);    ra += N_NODES;
  int*   cursor   = (int*)(ws + ra);    ra += N_NODES;
  int*   bsum     = (int*)(ws + ra);    ra += 256;
  float* h2tab    = ws + ra;            ra += (size_t)NL * TBL * HID;
  float* wtab     = ws + ra;            ra += (size_t)NL * TBL * 128;
  unsigned short* s_bf  = (unsigned short*)(ws + ra); ra += (size_t)N_NODES * C / 2;
  unsigned short* v_bf4 = (unsigned short*)(ws + ra); ra += (size_t)N_NODES * C * 2; // 4 ushorts/elem
  size_t req_sorted = ra * 4;

  // --- region B (fallback atomic path, aliases region A) ---
  size_t rb = off;
  float* agg_sf = ws + rb; rb += (size_t)N_NODES * C;
  float* agg_sg = ws + rb; rb += (size_t)N_NODES * C;
  float* agg_v  = ws + rb; rb += (size_t)N_NODES * C * 3;

  dim3 b256(256);
  const int gE  = (N_EDGES + 255) / 256;
  const int gNC = (N_NODES * C + 255) / 256;
  const int gN  = (N_NODES + 255) / 256;

  if (ws_size >= req_sorted) {
    hipMemsetAsync(counts, 0, 2 * N_NODES * sizeof(int) + 0, stream); // counts+row_start? NO:
    // counts and row_start are adjacent, but row_start is fully overwritten by scanC.
    // zero counts and cursor (cursor follows row_start): do precise memsets:
    hipMemsetAsync(cursor, 0, N_NODES * sizeof(int), stream);
    hipMemsetAsync(d_out, 0, NG * sizeof(float), stream);
    k_node_init<<<gNC, b256, 0, stream>>>(species, emb, s, s_bf);
    k_hist<<<gE, b256, 0, stream>>>(ei, counts);
    k_scanA<<<NBLK_N, b256, 0, stream>>>(counts, bsum);
    k_scanB<<<1, b256, 0, stream>>>(bsum);
    k_scanC<<<NBLK_N, b256, 0, stream>>>(counts, bsum, row_start);
    k_geom_scatter<<<gE, b256, 0, stream>>>(pos, ei, row_start, cursor, rec);
    k_table_h<<<(NL*TBL)/256, b256, 0, stream>>>(freqs, rW1, rb1, rW2, rb2, h2tab);
    k_table_w<<<(NL*TBL*16)/256, b256, 0, stream>>>(h2tab, rW3, rb3, wtab);

    // ---- layer 0 (v == 0: s-only gather; apply writes v directly) ----
    hipMemsetAsync(bn_sums, 0, 96 * sizeof(double), stream);
    k_agg_update<false><<<(N_NODES*C)/256, b256, 0, stream>>>(
        wtab, rec, row_start, counts, s_bf, v_bf4,
        Wss, bss, Wvv, s_new, v_new);
    k_bn_stats<<<BN_BLOCKS, b256, 0, stream>>>(s_new, v_new, bn_sums);
    k_apply<true><<<gNC, b256, 0, stream>>>(s_new, v_new, bn_sums,
        bn_gs, bn_gv, bn_bs, s, v, s_bf, v_bf4);

    // ---- layer 1 (s+v in one ushort4 gather) ----
    hipMemsetAsync(bn_sums, 0, 96 * sizeof(double), stream);
    k_agg_update<true><<<(N_NODES*C)/256, b256, 0, stream>>>(
        wtab + (size_t)TBL * 128, rec, row_start, counts, s_bf, v_bf4,
        Wss + C*C, bss + C, Wvv + C*C, s_new, v_new);
    k_bn_stats<<<BN_BLOCKS, b256, 0, stream>>>(s_new, v_new, bn_sums);
    k_apply<false><<<gNC, b256, 0, stream>>>(s_new, v_new, bn_sums,
        bn_gs + C, bn_gv + C, bn_bs + C, s, v, s_bf, v_bf4);

    k_readout<<<gN, b256, 0, stream>>>(s, species, batch, W_out, b_out, atom_ref, (float*)d_out);
  } else {
    hipMemsetAsync(v, 0, (size_t)N_NODES * C * 3 * sizeof(float), stream);
    k_node_init<<<gNC, b256, 0, stream>>>(species, emb, s, (unsigned short*)(ws + off));
    k_edge_geom<<<gE, b256, 0, stream>>>(pos, ei, freqs, basis, Y1);
    for (int l = 0; l < NL; l++) {
      hipMemsetAsync(agg_sf, 0, (size_t)N_NODES * 5 * C * sizeof(float), stream);
      hipMemsetAsync(bn_sums, 0, 96 * sizeof(double), stream);
      k_edge_msg_fb<<<gE, b256, 0, stream>>>(basis, Y1, ei, s, v,
          rW1 + l*NB*HID, rb1 + l*HID, rW2 + l*HID*HID, rb2 + l*HID,
          rW3 + l*HID*4*C, rb3 + l*4*C, agg_sf, agg_sg, agg_v);
      k_node_update_fb<<<(N_NODES*C)/256, b256, 0, stream>>>(agg_sf, agg_sg, agg_v,
          Wss + l*C*C, bss + l*C, Wvv + l*C*C, s_new, v_new, bn_sums);
      k_bn_scales_fb<<<1, 64, 0, stream>>>(bn_sums, bn_gs + l*C, bn_gv + l*C, scales);
      k_apply_fb<<<gNC, b256, 0, stream>>>(s_new, v_new, scales, bn_bs + l*C, s, v);
    }
    hipMemsetAsync(d_out, 0, NG * sizeof(float), stream);
    k_readout<<<gN, b256, 0, stream>>>(s, species, batch, W_out, b_out, atom_ref, (float*)d_out);
  }
}